// Round 11
// baseline (524.071 us; speedup 1.0000x reference)
//
#include <hip/hip_runtime.h>
#include <math.h>

#define D 256
#define DCAT 768
#define NPX 128
#define QSTR 896   // Q row stride: [outcat(768) | P(128)] bf16
#define CSTR 136   // padded LDS row stride (shorts) for epilogue transpose

typedef __attribute__((ext_vector_type(8))) short bf16x8;
typedef __attribute__((ext_vector_type(4))) float f32x4;

__device__ __forceinline__ short cvt_bf16(float f){
  union { float f; unsigned u; } v; v.f = f;
  unsigned r = v.u + 0x7FFF + ((v.u >> 16) & 1);   // RNE
  return (short)(r >> 16);
}
__device__ __forceinline__ float bf2f(short s){
  union { float f; unsigned u; } v; v.u = ((unsigned)(unsigned short)s) << 16;
  return v.f;
}

__device__ __forceinline__ float waveSum(float v){
#pragma unroll
  for(int o=32;o>=1;o>>=1) v += __shfl_xor(v,o,64);
  return v;
}
__device__ __forceinline__ float waveMax(float v){
#pragma unroll
  for(int o=32;o>=1;o>>=1) v = fmaxf(v,__shfl_xor(v,o,64));
  return v;
}

// merged: tanh(p), rowstart binary search, new_indices flag, p copy to output
__global__ void k_prep(const float* __restrict__ p, float* __restrict__ tp,
                       const int* __restrict__ adj_row, int* __restrict__ rs,
                       const int* __restrict__ idx, unsigned char* __restrict__ flag,
                       float* __restrict__ pout, int n, int e, int ksel){
  int i = blockIdx.x*blockDim.x+threadIdx.x;
  if(i<n){ float pv = p[i]; tp[i]=tanhf(pv); pout[i]=pv; }
  if(i<=n){
    int lo=0, hi=e;
    while(lo<hi){ int mid=(lo+hi)>>1; if(adj_row[mid]<i) lo=mid+1; else hi=mid; }
    rs[i]=lo;
  }
  if(i<ksel) flag[idx[i]] = 1;
}

__global__ void k_relprep(const float* __restrict__ rel_emb, const float* __restrict__ attn,
                          float* __restrict__ ss_rel, float* __restrict__ att_n,
                          short* __restrict__ reb, int R_){
  __shared__ float sm[4];
  int r = blockIdx.x; int d = threadIdx.x;
  float v = rel_emb[(size_t)r*D+d];
  reb[(size_t)r*D+d] = cvt_bf16(v);
  int lane=threadIdx.x&63, wid=threadIdx.x>>6;
  float s = waveSum(v*v);
  if(lane==0) sm[wid]=s;
  __syncthreads();
  if(threadIdx.x==0) ss_rel[r]=sm[0]+sm[1]+sm[2]+sm[3];
  __syncthreads();
  for(int l=0;l<2;l++){
    float dd = waveSum(v*attn[l*D+d]);
    if(lane==0) sm[wid]=dd;
    __syncthreads();
    if(threadIdx.x==0) att_n[(size_t)l*R_+r]=sm[0]+sm[1]+sm[2]+sm[3];
    __syncthreads();
  }
}

__global__ void k_relW(const float* __restrict__ rel_emb, const float* __restrict__ W,
                       const float* __restrict__ ak, short* __restrict__ rwb,
                       float* __restrict__ att_t, int R_){
  __shared__ float sm[4];
  int r=blockIdx.x, d=threadIdx.x;
  const float* row = rel_emb + (size_t)r*D;
  float acc=0.f;
#pragma unroll 4
  for(int k=0;k<D;k++) acc = fmaf(row[k], W[(size_t)k*D+d], acc);
  rwb[(size_t)r*D+d]=cvt_bf16(acc);
  int lane=threadIdx.x&63, wid=threadIdx.x>>6;
  float dd = waveSum(acc*ak[d]);
  if(lane==0) sm[wid]=dd;
  __syncthreads();
  if(threadIdx.x==0) att_t[r]=sm[0]+sm[1]+sm[2]+sm[3];
}

// one block per row: write Q cols 0..255 and init ssn[row] = sum of squares
__global__ void k_init0(const float* __restrict__ features, const float* __restrict__ tp,
                        short* __restrict__ Q, float* __restrict__ ssn, int n){
  __shared__ float sm[4];
  int row = blockIdx.x, d = threadIdx.x;
  float v = features[(size_t)row*D + d] * tp[row];
  Q[(size_t)row*QSTR + d] = cvt_bf16(v);
  int lane=d&63, wid=d>>6;
  float s = waveSum(v*v);
  if(lane==0) sm[wid]=s;
  __syncthreads();
  if(d==0) ssn[row] = sm[0]+sm[1]+sm[2]+sm[3];
}

// one wave per node; quarter-wave-parallel main loop (R9-proven exact version)
__global__ void k_agg(const int* __restrict__ rs, const int* __restrict__ adj_col,
                      const int* __restrict__ rel_ids, const float* __restrict__ rel_vals,
                      const unsigned char* __restrict__ flag, const float* __restrict__ tp,
                      const float* __restrict__ ss_rel, const float* __restrict__ att_n,
                      const float* __restrict__ att_t, const short* __restrict__ reb,
                      const short* __restrict__ rwb, short* __restrict__ Q,
                      float* __restrict__ ssn, int n, int layer){
  int wid = threadIdx.x>>6, lane = threadIdx.x&63;
  int node = blockIdx.x*4 + wid;
  if(node>=n) return;
  int s = rs[node], e = rs[node+1];
  float accq[16];
#pragma unroll
  for(int k=0;k<16;k++) accq[k]=0.f;
  if(e > s){
    float mx = -INFINITY;
    for(int i=s+lane;i<e;i+=64){
      int rid = rel_ids[i]; float rv = rel_vals[i];
      float a = 0.f;
      if(rv>0.f){
        float t = tp[adj_col[i]];
        float sc = rv*rsqrtf(fmaxf(rv*rv*ss_rel[rid],1e-12f));
        a = t*sc*(flag[i]? att_t[rid] : att_n[rid]);
      }
      mx = fmaxf(mx,a);
    }
    mx = waveMax(mx);
    float se = 0.f;
    for(int i=s+lane;i<e;i+=64){
      int rid = rel_ids[i]; float rv = rel_vals[i];
      float a = 0.f;
      if(rv>0.f){
        float t = tp[adj_col[i]];
        float sc = rv*rsqrtf(fmaxf(rv*rv*ss_rel[rid],1e-12f));
        a = t*sc*(flag[i]? att_t[rid] : att_n[rid]);
      }
      se += __expf(a-mx);
    }
    se = waveSum(se);
    float inv = 1.f/se;
    int qid = lane>>4, ql = lane&15;
    for(int i0=s; i0<e; i0+=4){
      int j = i0 + qid;
      float w=0.f, coef=0.f;
      float nbv[16], rbv[16];
#pragma unroll
      for(int k=0;k<16;k++){ nbv[k]=0.f; rbv[k]=0.f; }
      if(j < e){
        int rid = rel_ids[j]; float rv = rel_vals[j]; int col = adj_col[j];
        const short* np = Q + (size_t)col*QSTR + layer*D + ql*16;
        bf16x8 n0 = *(const bf16x8*)np;
        bf16x8 n1 = *(const bf16x8*)(np+8);
#pragma unroll
        for(int k=0;k<8;k++){ nbv[k]=bf2f(n0[k]); nbv[k+8]=bf2f(n1[k]); }
        if(rv>0.f){
          float t = tp[col];
          float sc = rv*rsqrtf(fmaxf(rv*rv*ss_rel[rid],1e-12f));
          bool f = flag[j];
          const short* rp = (f? rwb : reb) + (size_t)rid*D + ql*16;
          bf16x8 r0 = *(const bf16x8*)rp;
          bf16x8 r1 = *(const bf16x8*)(rp+8);
#pragma unroll
          for(int k=0;k<8;k++){ rbv[k]=bf2f(r0[k]); rbv[k+8]=bf2f(r1[k]); }
          float dp = 0.f;
#pragma unroll
          for(int k=0;k<16;k++) dp += nbv[k]*rbv[k];
#pragma unroll
          for(int o=1;o<16;o<<=1) dp += __shfl_xor(dp,o,64);
          float a = t*sc*(f? att_t[rid] : att_n[rid]);
          w = __expf(a-mx)*inv;
          coef = 2.f*t*t*sc*sc*dp;
        } else {
          w = __expf(-mx)*inv;
        }
      }
#pragma unroll
      for(int k=0;k<16;k++) accq[k] += w*(nbv[k] - coef*rbv[k]);
    }
  }
#pragma unroll
  for(int k=0;k<16;k++){
    float v = accq[k];
    v += __shfl_xor(v,16,64);
    v += __shfl_xor(v,32,64);
    accq[k] = v;
  }
  if(lane < 16){
    float t0 = tp[node];
    bf16x8 o0, o1;
    float pss = 0.f;
#pragma unroll
    for(int k=0;k<8;k++){
      o0[k]=cvt_bf16(accq[k]*t0); o1[k]=cvt_bf16(accq[k+8]*t0);
      pss += accq[k]*accq[k] + accq[k+8]*accq[k+8];
    }
    short* op = Q + (size_t)node*QSTR + (layer+1)*D + lane*16;
    *(bf16x8*)op = o0;
    *(bf16x8*)(op+8) = o1;
#pragma unroll
    for(int o=1;o<16;o<<=1) pss += __shfl_xor(pss,o,64);
    if(lane==0) ssn[node] += pss * t0 * t0;
  }
}

__global__ void k_proxynorm(const float* __restrict__ proxy, short* __restrict__ pn){
  __shared__ float sm[4];
  int j = blockIdx.x;
  float ssum=0.f;
  for(int d=threadIdx.x; d<DCAT; d+=256){ float v=proxy[(size_t)j*DCAT+d]; ssum+=v*v; }
  int lane=threadIdx.x&63, wid=threadIdx.x>>6;
  ssum = waveSum(ssum);
  if(lane==0) sm[wid]=ssum;
  __syncthreads();
  float scale = rsqrtf(fmaxf(sm[0]+sm[1]+sm[2]+sm[3],1e-12f));
  for(int d=threadIdx.x; d<DCAT; d+=256)
    pn[(size_t)j*DCAT + d] = cvt_bf16(proxy[(size_t)j*DCAT+d]*scale);
}

__global__ void k_cast(const float* __restrict__ in, short* __restrict__ out, long total){
  long i = (long)blockIdx.x*blockDim.x+threadIdx.x;
  if(i<total) out[i]=cvt_bf16(in[i]);
}

__global__ void k_tcast(const float* __restrict__ in, short* __restrict__ out,
                        int R, int C, int ldo, int coff, float sign){
  __shared__ float tile[32][33];
  int bx = blockIdx.x*32, by = blockIdx.y*32;
  for(int i=threadIdx.y;i<32;i+=8){
    int rr = by+i, cc = bx+threadIdx.x;
    if(rr<R && cc<C) tile[i][threadIdx.x] = in[(size_t)rr*C + cc];
  }
  __syncthreads();
  for(int i=threadIdx.y;i<32;i+=8){
    int cc = bx+i, rr = by+threadIdx.x;
    if(cc<C && rr<R) out[(size_t)cc*ldo + coff + rr] = cvt_bf16(sign*tile[threadIdx.x][i]);
  }
}

// ---------------- generic MFMA GEMM (ring-3, fp32 out) — used for Mx only ----------
template<int LDA_, int LDB_, int NTOT, int KC>
__global__ __launch_bounds__(256,2) void k_gemm(
    const short* __restrict__ A, const short* __restrict__ Bt,
    float* __restrict__ outF, int M)
{
  __shared__ short smem[3][2][128*32];
  const int tid = threadIdx.x;
  const int lane = tid & 63, w = tid >> 6;
  const int wm = w >> 1, wn = w & 1;
  const int bn = blockIdx.x * 128, bm = blockIdx.y * 128;

  const short* Ag = A  + (size_t)bm * LDA_;
  const short* Bg = Bt + (size_t)bn * LDB_;

  auto stage = [&](int buf, int k0){
#pragma unroll
    for(int c=0;c<2;++c){
      int u = c*256 + tid;
      int row = u >> 2;
      int cb = ((u & 3) ^ ((u >> 3) & 3)) * 8;
      __builtin_amdgcn_global_load_lds(
        (const __attribute__((address_space(1))) unsigned int*)(Ag + (size_t)row*LDA_ + k0 + cb),
        (__attribute__((address_space(3))) unsigned int*)&smem[buf][0][u*8], 16, 0, 0);
      __builtin_amdgcn_global_load_lds(
        (const __attribute__((address_space(1))) unsigned int*)(Bg + (size_t)row*LDB_ + k0 + cb),
        (__attribute__((address_space(3))) unsigned int*)&smem[buf][1][u*8], 16, 0, 0);
    }
  };

  f32x4 acc[4][4] = {};
  const int lr = lane & 15, kg = lane >> 4;
  const int ksw = (kg ^ ((lr >> 1) & 3)) * 8;
  constexpr int NT = KC / 32;

  stage(0, 0);
  stage(1, 32);
  for(int t=0; t<NT; ++t){
    if(t+1 < NT) asm volatile("s_waitcnt vmcnt(4)" ::: "memory");
    else         asm volatile("s_waitcnt vmcnt(0)" ::: "memory");
    __builtin_amdgcn_s_barrier();
    __builtin_amdgcn_sched_barrier(0);
    const short* Al = &smem[t%3][0][0];
    const short* Bl = &smem[t%3][1][0];
    bf16x8 af[4], bfr[4];
#pragma unroll
    for(int i=0;i<4;++i) af[i] = *(const bf16x8*)(Al + (wm*64 + i*16 + lr)*32 + ksw);
#pragma unroll
    for(int j=0;j<4;++j) bfr[j] = *(const bf16x8*)(Bl + (wn*64 + j*16 + lr)*32 + ksw);
    if(t+2 < NT) stage((t+2)%3, (t+2)*32);
    __builtin_amdgcn_s_setprio(1);
#pragma unroll
    for(int i=0;i<4;++i)
#pragma unroll
      for(int j=0;j<4;++j)
        acc[i][j] = __builtin_amdgcn_mfma_f32_16x16x32_bf16(af[i], bfr[j], acc[i][j], 0, 0, 0);
    __builtin_amdgcn_s_setprio(0);
  }

  const int row0 = bm + wm*64 + (lane>>4)*4;
  const int col0 = bn + wn*64 + lr;
#pragma unroll
  for(int i=0;i<4;++i)
#pragma unroll
    for(int j=0;j<4;++j)
#pragma unroll
      for(int r=0;r<4;++r){
        int row = row0 + i*16 + r;
        if(row < M) outF[(size_t)row*NTOT + col0 + j*16] = acc[i][j][r];
      }
}

// ---------------- k_pr: proxy-att logits GEMM (K=768) + fused row softmax ---------
__global__ __launch_bounds__(256,2) void k_pr(
    short* __restrict__ Q, const short* __restrict__ pn,
    const float* __restrict__ ssn, int M)
{
  __shared__ short smem[3][2][128*32];
  const int tid = threadIdx.x, lane = tid & 63, w = tid >> 6;
  const int wm = w >> 1, wn = w & 1;
  int nwg = gridDim.y;
  int orig = blockIdx.y;
  int q = nwg>>3, rm = nwg&7, xcd = orig&7, lid = orig>>3;
  int wg = (xcd<rm ? xcd*(q+1) : rm*(q+1)+(xcd-rm)*q) + lid;
  const int bm = wg*128;

  const short* Ag = Q + (size_t)bm * QSTR;
  const short* Bg = pn;

  auto stage = [&](int buf, int k0){
#pragma unroll
    for(int c=0;c<2;++c){
      int u = c*256 + tid;
      int row = u >> 2;
      int cb = ((u & 3) ^ ((u >> 3) & 3)) * 8;
      __builtin_amdgcn_global_load_lds(
        (const __attribute__((address_space(1))) unsigned int*)(Ag + (size_t)row*QSTR + k0 + cb),
        (__attribute__((address_space(3))) unsigned int*)&smem[buf][0][u*8], 16, 0, 0);
      __builtin_amdgcn_global_load_lds(
        (const __attribute__((address_space(1))) unsigned int*)(Bg + (size_t)row*DCAT + k0 + cb),
        (__attribute__((address_space(3))) unsigned int*)&smem[buf][1][u*8], 16, 0, 0);
    }
  };

  f32x4 acc[4][4] = {};
  const int lr = lane & 15, kg = lane >> 4;
  const int ksw = (kg ^ ((lr >> 1) & 3)) * 8;
  constexpr int NT = DCAT / 32;

  stage(0, 0);
  stage(1, 32);
  for(int t=0; t<NT; ++t){
    if(t+1 < NT) asm volatile("s_waitcnt vmcnt(4)" ::: "memory");
    else         asm volatile("s_waitcnt vmcnt(0)" ::: "memory");
    __builtin_amdgcn_s_barrier();
    __builtin_amdgcn_sched_barrier(0);
    const short* Al = &smem[t%3][0][0];
    const short* Bl = &smem[t%3][1][0];
    bf16x8 af[4], bfr[4];
#pragma unroll
    for(int i=0;i<4;++i) af[i] = *(const bf16x8*)(Al + (wm*64 + i*16 + lr)*32 + ksw);
#pragma unroll
    for(int j=0;j<4;++j) bfr[j] = *(const bf16x8*)(Bl + (wn*64 + j*16 + lr)*32 + ksw);
    if(t+2 < NT) stage((t+2)%3, (t+2)*32);
    __builtin_amdgcn_s_setprio(1);
#pragma unroll
    for(int i=0;i<4;++i)
#pragma unroll
      for(int j=0;j<4;++j)
        acc[i][j] = __builtin_amdgcn_mfma_f32_16x16x32_bf16(af[i], bfr[j], acc[i][j], 0, 0, 0);
    __builtin_amdgcn_s_setprio(0);
  }

  // logits -> LDS bf16 [128][132]
  __syncthreads();
  short* lg = (short*)smem;
  const int row0l = wm*64 + kg*4;
  const int col0l = wn*64 + lr;
#pragma unroll
  for(int i=0;i<4;++i){
#pragma unroll
    for(int j=0;j<4;++j){
#pragma unroll
      for(int r=0;r<4;++r){
        int rl = row0l + i*16 + r;
        int rg = bm + rl;
        float s = (rg < M) ? rsqrtf(fmaxf(ssn[rg],1e-12f)) : 0.f;
        lg[rl*132 + col0l + j*16] = cvt_bf16(acc[i][j][r] * s);
      }
    }
  }
  __syncthreads();
  for(int k2=0;k2<32;++k2){
    int rl = w*32 + k2;
    float a = bf2f(lg[rl*132 + lane]);
    float b = bf2f(lg[rl*132 + 64 + lane]);
    float m = waveMax(fmaxf(a,b));
    float ea = __expf(a-m), eb = __expf(b-m);
    float sm_ = waveSum(ea+eb);
    float inv = 1.f/sm_;
    size_t rg = (size_t)(bm + rl);
    Q[rg*QSTR + DCAT + lane]      = cvt_bf16(ea*inv);
    Q[rg*QSTR + DCAT + 64 + lane] = cvt_bf16(eb*inv);
  }
}

// ---------------- k_go: fused gate GEMM + output (128² ring-3) ---------------------
// phase A1: pv = P @ Bt2^T (K=128 direct global) -> pvb bf16
// phase A2: acc = P @ (-MxT)^T (K=128 direct global)  == gate P-part
// main loop: acc += oc @ gkT^T (K=768, ring-3 counted vmcnt)
// epilogue: out = oc - (1-sigmoid(acc))*pv
__global__ __launch_bounds__(256,2) void k_go(
    short* __restrict__ Q, const short* __restrict__ BG,
    const short* __restrict__ Bt2, float* __restrict__ outF, int M)
{
  __shared__ short smem[3][2][128*32];
  const int tid = threadIdx.x, lane = tid & 63, w = tid >> 6;
  const int wm = w >> 1, wn = w & 1;
  const int gx = gridDim.x;
  int nwg = gx*gridDim.y;
  int orig = blockIdx.y*gx + blockIdx.x;
  int q = nwg>>3, rm = nwg&7, xcd = orig&7, lid = orig>>3;
  int wg = (xcd<rm ? xcd*(q+1) : rm*(q+1)+(xcd-rm)*q) + lid;
  const int bn = (wg%gx)*128, bm = (wg/gx)*128;
  const int lr = lane & 15, kg = lane >> 4;

  const short* Ag = Q  + (size_t)bm * QSTR;
  const short* Bg = BG + (size_t)bn * QSTR;

  auto stage = [&](int buf, int k0){
#pragma unroll
    for(int c=0;c<2;++c){
      int u = c*256 + tid;
      int row = u >> 2;
      int cb = ((u & 3) ^ ((u >> 3) & 3)) * 8;
      __builtin_amdgcn_global_load_lds(
        (const __attribute__((address_space(1))) unsigned int*)(Ag + (size_t)row*QSTR + k0 + cb),
        (__attribute__((address_space(3))) unsigned int*)&smem[buf][0][u*8], 16, 0, 0);
      __builtin_amdgcn_global_load_lds(
        (const __attribute__((address_space(1))) unsigned int*)(Bg + (size_t)row*QSTR + k0 + cb),
        (__attribute__((address_space(3))) unsigned int*)&smem[buf][1][u*8], 16, 0, 0);
    }
  };

  stage(0, 0);
  stage(1, 32);

  // ---- phase A1: pv = P @ Bt2^T (K=128, direct global MFMA) ----
  f32x4 acc[4][4] = {};
#pragma unroll
  for(int ks=0; ks<4; ++ks){
    bf16x8 af[4], bb[4];
#pragma unroll
    for(int i=0;i<4;++i)
      af[i] = *(const bf16x8*)(Q + (size_t)(bm + wm*64 + i*16 + lr)*QSTR + DCAT + ks*32 + kg*8);
#pragma unroll
    for(int j=0;j<4;++j)
      bb[j] = *(const bf16x8*)(Bt2 + (size_t)(bn + wn*64 + j*16 + lr)*NPX + ks*32 + kg*8);
#pragma unroll
    for(int i=0;i<4;++i)
#pragma unroll
      for(int j=0;j<4;++j)
        acc[i][j] = __builtin_amdgcn_mfma_f32_16x16x32_bf16(af[i], bb[j], acc[i][j], 0, 0, 0);
  }
  short4 pvb[4][4];
#pragma unroll
  for(int i=0;i<4;++i)
#pragma unroll
    for(int j=0;j<4;++j){
      pvb[i][j].x = cvt_bf16(acc[i][j][0]);
      pvb[i][j].y = cvt_bf16(acc[i][j][1]);
      pvb[i][j].z = cvt_bf16(acc[i][j][2]);
      pvb[i][j].w = cvt_bf16(acc[i][j][3]);
      acc[i][j] = (f32x4){0.f,0.f,0.f,0.f};
    }

  // ---- phase A2: acc = P @ (-MxT)^T (gate P-part, K=128, direct global) ----
#pragma unroll
  for(int ks=0; ks<4; ++ks){
    bf16x8 af[4], bb[4];
#pragma unroll
    for(int i=0;i<4;++i)
      af[i] = *(const bf16x8*)(Q + (size_t)(bm + wm*64 + i*16 + lr)*QSTR + DCAT + ks*32 + kg*8);
#pragma unroll
    for(int j=0;j<4;++j)
      bb[j] = *(const bf16x8*)(BG + (size_t)(bn + wn*64 + j*16 + lr)*QSTR + DCAT + ks*32 + kg*8);
#pragma unroll
    for(int i=0;i<4;++i)
#pragma unroll
      for(int j=0;j<4;++j)
        acc[i][j] = __builtin_amdgcn_mfma_f32_16x16x32_bf16(af[i], bb[j], acc[i][j], 0, 0, 0);
  }

  // ---- main loop: acc += oc @ gkT^T, K=768, ring-3 counted vmcnt ----
  const int ksw = (kg ^ ((lr >> 1) & 3)) * 8;
  constexpr int NT = DCAT / 32;   // 24
  for(int t=0; t<NT; ++t){
    if(t+1 < NT) asm volatile("s_waitcnt vmcnt(4)" ::: "memory");
    else         asm volatile("s_waitcnt vmcnt(0)" ::: "memory");
    __builtin_amdgcn_s_barrier();
    __builtin_amdgcn_sched_barrier(0);
    const short* Al = &smem[t%3][0][0];
    const short* Bl = &smem[t%3][1][0];
    bf16x8 af[4], bfr[4];
#pragma unroll
    for(int i=0;i<4;++i) af[i] = *(const bf16x8*)(Al + (wm*64 + i*16 + lr)*32 + ksw);
#pragma unroll
    for(int j=0;j<4;++j) bfr[j] = *(const bf16x8*)(Bl + (wn*64 + j*16 + lr)*32 + ksw);
    if(t+2 < NT) stage((t+2)%3, (t+2)*32);
    __builtin_amdgcn_s_setprio(1);
#pragma unroll
    for(int i=0;i<4;++i)
#pragma unroll
      for(int j=0;j<4;++j)
        acc[i][j] = __builtin_amdgcn_mfma_f32_16x16x32_bf16(af[i], bfr[j], acc[i][j], 0, 0, 0);
    __builtin_amdgcn_s_setprio(0);
  }

  // ---- epilogue: out = oc - (1-g)*pv ----
  __syncthreads();
  short* cst = (short*)smem;
  const int row0l = wm*64 + kg*4;
  const int col0l = wn*64 + lr;
#pragma unroll
  for(int i=0;i<4;++i){
#pragma unroll
    for(int j=0;j<4;++j){
      float pv4[4] = { bf2f(pvb[i][j].x), bf2f(pvb[i][j].y), bf2f(pvb[i][j].z), bf2f(pvb[i][j].w) };
#pragma unroll
      for(int r2=0;r2<4;++r2){
        float g = 1.f/(1.f+__expf(-acc[i][j][r2]));
        cst[(row0l + i*16 + r2)*CSTR + col0l + j*16] = cvt_bf16((1.f-g)*pv4[r2]);
      }
    }
  }
  __syncthreads();
  const int rl0 = tid>>4, c0 = (tid&15)*8;
#pragma unroll
  for(int rr=0; rr<8; ++rr){
    int rl = rl0 + rr*16;
    int rg = bm + rl;
    if(rg >= M) continue;
    bf16x8 c8  = *(const bf16x8*)(cst + rl*CSTR + c0);
    bf16x8 oc8 = *(const bf16x8*)(Q + (size_t)rg*QSTR + bn + c0);
    float ov[8];
#pragma unroll
    for(int k=0;k<8;k++) ov[k] = bf2f(oc8[k]) - bf2f(c8[k]);
    *(float4*)(outF + (size_t)rg*DCAT + bn + c0)     = make_float4(ov[0],ov[1],ov[2],ov[3]);
    *(float4*)(outF + (size_t)rg*DCAT + bn + c0 + 4) = make_float4(ov[4],ov[5],ov[6],ov[7]);
  }
}

extern "C" void kernel_launch(void* const* d_in, const int* in_sizes, int n_in,
                              void* d_out, int out_size, void* d_ws, size_t ws_size,
                              hipStream_t stream){
  const float* features = (const float*)d_in[0];
  const float* rel_emb  = (const float*)d_in[1];
  const float* p        = (const float*)d_in[2];
  const float* w_keys   = (const float*)d_in[3];
  const float* attn     = (const float*)d_in[4];
  const float* proxy    = (const float*)d_in[5];
  const float* gatek    = (const float*)d_in[6];
  const float* rel_vals = (const float*)d_in[7];
  const int* adj_row    = (const int*)d_in[8];
  const int* adj_col    = (const int*)d_in[9];
  const int* rel_ids    = (const int*)d_in[10];
  const int* new_idx    = (const int*)d_in[11];

  const int n    = in_sizes[2];
  const int r    = in_sizes[1]/D;
  const int e    = in_sizes[7];
  const int ksel = in_sizes[11];
  const size_t Mpad = ((size_t)n + 127) & ~(size_t)127;

  char* ws = (char*)d_ws;
  size_t off=0;
  auto alloc=[&](size_t bytes)->void*{ void* pp = ws+off; off=(off+bytes+255)&~(size_t)255; return pp; };
  float* tp      = (float*)alloc((size_t)n*4);
  int*   rs      = (int*)alloc((size_t)(n+1)*4);
  unsigned char* flag = (unsigned char*)alloc((size_t)e);
  float* ss_rel  = (float*)alloc((size_t)r*4);
  float* att_n   = (float*)alloc((size_t)2*r*4);
  float* att_t   = (float*)alloc((size_t)2*r*4);
  short* reb     = (short*)alloc((size_t)r*D*2);
  short* rwb     = (short*)alloc((size_t)2*r*D*2);
  short* pn      = (short*)alloc((size_t)NPX*DCAT*2);
  short* proxyb  = (short*)alloc((size_t)NPX*DCAT*2);
  short* Bt2     = (short*)alloc((size_t)DCAT*NPX*2);
  short* BG      = (short*)alloc((size_t)DCAT*QSTR*2);
  float* MxF     = (float*)alloc((size_t)NPX*DCAT*4);
  float* ssn     = (float*)alloc(Mpad*4);
  short* Q       = (short*)alloc(Mpad*QSTR*2);

  float* outF = (float*)d_out;
  float* pout = (float*)d_out + (size_t)n*DCAT;

  hipMemsetAsync(flag, 0, (size_t)e, stream);
  hipMemsetAsync(Q + (size_t)n*QSTR, 0, (Mpad-(size_t)n)*QSTR*2, stream);

  int prep_n = (ksel > n+1 ? ksel : n+1);
  k_prep<<<(prep_n+255)/256,256,0,stream>>>(p,tp,adj_row,rs,new_idx,flag,pout,n,e,ksel);
  k_relprep<<<r,256,0,stream>>>(rel_emb,attn,ss_rel,att_n,reb,r);
  for(int l=0;l<2;l++)
    k_relW<<<r,256,0,stream>>>(rel_emb, w_keys+(size_t)l*D*D, attn+(size_t)l*D,
                               rwb+(size_t)l*r*D, att_t+(size_t)l*r, r);
  k_proxynorm<<<NPX,256,0,stream>>>(proxy,pn);
  {
    long tpx = (long)NPX*DCAT;
    k_cast<<<(int)((tpx+255)/256),256,0,stream>>>(proxy, proxyb, tpx);
    dim3 tb(32,8);
    k_tcast<<<dim3(DCAT/32, DCAT/32), tb, 0, stream>>>(gatek, BG, DCAT, DCAT, QSTR, 0, 1.f);
    k_gemm<DCAT, QSTR, DCAT, DCAT><<<dim3(DCAT/128,1),256,0,stream>>>(proxyb, BG, MxF, NPX);
    k_tcast<<<dim3(DCAT/32, NPX/32), tb, 0, stream>>>(MxF, BG, NPX, DCAT, QSTR, DCAT, -1.f);
    k_tcast<<<dim3(DCAT/32, NPX/32), tb, 0, stream>>>(proxy, Bt2, NPX, DCAT, NPX, 0, 1.f);
  }
  k_init0<<<n,256,0,stream>>>(features,tp,Q,ssn,n);
  for(int l=0;l<2;l++)
    k_agg<<<(n+3)/4,256,0,stream>>>(rs,adj_col,rel_ids,rel_vals,flag,tp,ss_rel,
                                    att_n+(size_t)l*r, att_t+(size_t)l*r, reb,
                                    rwb+(size_t)l*r*D, Q, ssn, n, l);

  int mt = (int)(Mpad/128);
  // k_pr: proxy-att logits + fused l2n + softmax -> probs into Q[:,768:896]
  k_pr<<<dim3(1, mt),256,0,stream>>>(Q, pn, ssn, n);
  // k_go: fused gate + output (K=768 main loop; P-part folded into phase A)
  k_go<<<dim3(DCAT/128, mt),256,0,stream>>>(Q, BG, Bt2, outF, n);
}

// Round 12
// 505.477 us; speedup vs baseline: 1.0368x; 1.0368x over previous
//
#include <hip/hip_runtime.h>
#include <math.h>

#define D 256
#define DCAT 768
#define NPX 128
#define QSTR 896   // Q row stride: [outcat(768) | P(128)] bf16
#define CSTR 136   // padded LDS row stride (shorts) for epilogue transpose

typedef __attribute__((ext_vector_type(8))) short bf16x8;
typedef __attribute__((ext_vector_type(4))) float f32x4;

__device__ __forceinline__ short cvt_bf16(float f){
  union { float f; unsigned u; } v; v.f = f;
  unsigned r = v.u + 0x7FFF + ((v.u >> 16) & 1);   // RNE
  return (short)(r >> 16);
}
__device__ __forceinline__ float bf2f(short s){
  union { float f; unsigned u; } v; v.u = ((unsigned)(unsigned short)s) << 16;
  return v.f;
}

__device__ __forceinline__ float waveSum(float v){
#pragma unroll
  for(int o=32;o>=1;o>>=1) v += __shfl_xor(v,o,64);
  return v;
}
__device__ __forceinline__ float waveMax(float v){
#pragma unroll
  for(int o=32;o>=1;o>>=1) v = fmaxf(v,__shfl_xor(v,o,64));
  return v;
}

// merged: tanh(p), rowstart binary search, new_indices flag, p copy to output
__global__ void k_prep(const float* __restrict__ p, float* __restrict__ tp,
                       const int* __restrict__ adj_row, int* __restrict__ rs,
                       const int* __restrict__ idx, unsigned char* __restrict__ flag,
                       float* __restrict__ pout, int n, int e, int ksel){
  int i = blockIdx.x*blockDim.x+threadIdx.x;
  if(i<n){ float pv = p[i]; tp[i]=tanhf(pv); pout[i]=pv; }
  if(i<=n){
    int lo=0, hi=e;
    while(lo<hi){ int mid=(lo+hi)>>1; if(adj_row[mid]<i) lo=mid+1; else hi=mid; }
    rs[i]=lo;
  }
  if(i<ksel) flag[idx[i]] = 1;
}

__global__ void k_relprep(const float* __restrict__ rel_emb, const float* __restrict__ attn,
                          float* __restrict__ ss_rel, float* __restrict__ att_n,
                          short* __restrict__ reb, int R_){
  __shared__ float sm[4];
  int r = blockIdx.x; int d = threadIdx.x;
  float v = rel_emb[(size_t)r*D+d];
  reb[(size_t)r*D+d] = cvt_bf16(v);
  int lane=threadIdx.x&63, wid=threadIdx.x>>6;
  float s = waveSum(v*v);
  if(lane==0) sm[wid]=s;
  __syncthreads();
  if(threadIdx.x==0) ss_rel[r]=sm[0]+sm[1]+sm[2]+sm[3];
  __syncthreads();
  for(int l=0;l<2;l++){
    float dd = waveSum(v*attn[l*D+d]);
    if(lane==0) sm[wid]=dd;
    __syncthreads();
    if(threadIdx.x==0) att_n[(size_t)l*R_+r]=sm[0]+sm[1]+sm[2]+sm[3];
    __syncthreads();
  }
}

__global__ void k_relW(const float* __restrict__ rel_emb, const float* __restrict__ W,
                       const float* __restrict__ ak, short* __restrict__ rwb,
                       float* __restrict__ att_t, int R_){
  __shared__ float sm[4];
  int r=blockIdx.x, d=threadIdx.x;
  const float* row = rel_emb + (size_t)r*D;
  float acc=0.f;
#pragma unroll 4
  for(int k=0;k<D;k++) acc = fmaf(row[k], W[(size_t)k*D+d], acc);
  rwb[(size_t)r*D+d]=cvt_bf16(acc);
  int lane=threadIdx.x&63, wid=threadIdx.x>>6;
  float dd = waveSum(acc*ak[d]);
  if(lane==0) sm[wid]=dd;
  __syncthreads();
  if(threadIdx.x==0) att_t[r]=sm[0]+sm[1]+sm[2]+sm[3];
}

// one block per row: write Q cols 0..255 and init ssn[row] = sum of squares
__global__ void k_init0(const float* __restrict__ features, const float* __restrict__ tp,
                        short* __restrict__ Q, float* __restrict__ ssn, int n){
  __shared__ float sm[4];
  int row = blockIdx.x, d = threadIdx.x;
  float v = features[(size_t)row*D + d] * tp[row];
  Q[(size_t)row*QSTR + d] = cvt_bf16(v);
  int lane=d&63, wid=d>>6;
  float s = waveSum(v*v);
  if(lane==0) sm[wid]=s;
  __syncthreads();
  if(d==0) ssn[row] = sm[0]+sm[1]+sm[2]+sm[3];
}

// one wave per node; quarter-wave-parallel main loop (R9-proven exact version)
__global__ void k_agg(const int* __restrict__ rs, const int* __restrict__ adj_col,
                      const int* __restrict__ rel_ids, const float* __restrict__ rel_vals,
                      const unsigned char* __restrict__ flag, const float* __restrict__ tp,
                      const float* __restrict__ ss_rel, const float* __restrict__ att_n,
                      const float* __restrict__ att_t, const short* __restrict__ reb,
                      const short* __restrict__ rwb, short* __restrict__ Q,
                      float* __restrict__ ssn, int n, int layer){
  int wid = threadIdx.x>>6, lane = threadIdx.x&63;
  int node = blockIdx.x*4 + wid;
  if(node>=n) return;
  int s = rs[node], e = rs[node+1];
  float accq[16];
#pragma unroll
  for(int k=0;k<16;k++) accq[k]=0.f;
  if(e > s){
    float mx = -INFINITY;
    for(int i=s+lane;i<e;i+=64){
      int rid = rel_ids[i]; float rv = rel_vals[i];
      float a = 0.f;
      if(rv>0.f){
        float t = tp[adj_col[i]];
        float sc = rv*rsqrtf(fmaxf(rv*rv*ss_rel[rid],1e-12f));
        a = t*sc*(flag[i]? att_t[rid] : att_n[rid]);
      }
      mx = fmaxf(mx,a);
    }
    mx = waveMax(mx);
    float se = 0.f;
    for(int i=s+lane;i<e;i+=64){
      int rid = rel_ids[i]; float rv = rel_vals[i];
      float a = 0.f;
      if(rv>0.f){
        float t = tp[adj_col[i]];
        float sc = rv*rsqrtf(fmaxf(rv*rv*ss_rel[rid],1e-12f));
        a = t*sc*(flag[i]? att_t[rid] : att_n[rid]);
      }
      se += __expf(a-mx);
    }
    se = waveSum(se);
    float inv = 1.f/se;
    int qid = lane>>4, ql = lane&15;
    for(int i0=s; i0<e; i0+=4){
      int j = i0 + qid;
      float w=0.f, coef=0.f;
      float nbv[16], rbv[16];
#pragma unroll
      for(int k=0;k<16;k++){ nbv[k]=0.f; rbv[k]=0.f; }
      if(j < e){
        int rid = rel_ids[j]; float rv = rel_vals[j]; int col = adj_col[j];
        const short* np = Q + (size_t)col*QSTR + layer*D + ql*16;
        bf16x8 n0 = *(const bf16x8*)np;
        bf16x8 n1 = *(const bf16x8*)(np+8);
#pragma unroll
        for(int k=0;k<8;k++){ nbv[k]=bf2f(n0[k]); nbv[k+8]=bf2f(n1[k]); }
        if(rv>0.f){
          float t = tp[col];
          float sc = rv*rsqrtf(fmaxf(rv*rv*ss_rel[rid],1e-12f));
          bool f = flag[j];
          const short* rp = (f? rwb : reb) + (size_t)rid*D + ql*16;
          bf16x8 r0 = *(const bf16x8*)rp;
          bf16x8 r1 = *(const bf16x8*)(rp+8);
#pragma unroll
          for(int k=0;k<8;k++){ rbv[k]=bf2f(r0[k]); rbv[k+8]=bf2f(r1[k]); }
          float dp = 0.f;
#pragma unroll
          for(int k=0;k<16;k++) dp += nbv[k]*rbv[k];
#pragma unroll
          for(int o=1;o<16;o<<=1) dp += __shfl_xor(dp,o,64);
          float a = t*sc*(f? att_t[rid] : att_n[rid]);
          w = __expf(a-mx)*inv;
          coef = 2.f*t*t*sc*sc*dp;
        } else {
          w = __expf(-mx)*inv;
        }
      }
#pragma unroll
      for(int k=0;k<16;k++) accq[k] += w*(nbv[k] - coef*rbv[k]);
    }
  }
#pragma unroll
  for(int k=0;k<16;k++){
    float v = accq[k];
    v += __shfl_xor(v,16,64);
    v += __shfl_xor(v,32,64);
    accq[k] = v;
  }
  if(lane < 16){
    float t0 = tp[node];
    bf16x8 o0, o1;
    float pss = 0.f;
#pragma unroll
    for(int k=0;k<8;k++){
      o0[k]=cvt_bf16(accq[k]*t0); o1[k]=cvt_bf16(accq[k+8]*t0);
      pss += accq[k]*accq[k] + accq[k+8]*accq[k+8];
    }
    short* op = Q + (size_t)node*QSTR + (layer+1)*D + lane*16;
    *(bf16x8*)op = o0;
    *(bf16x8*)(op+8) = o1;
#pragma unroll
    for(int o=1;o<16;o<<=1) pss += __shfl_xor(pss,o,64);
    if(lane==0) ssn[node] += pss * t0 * t0;
  }
}

__global__ void k_proxynorm(const float* __restrict__ proxy, short* __restrict__ pn){
  __shared__ float sm[4];
  int j = blockIdx.x;
  float ssum=0.f;
  for(int d=threadIdx.x; d<DCAT; d+=256){ float v=proxy[(size_t)j*DCAT+d]; ssum+=v*v; }
  int lane=threadIdx.x&63, wid=threadIdx.x>>6;
  ssum = waveSum(ssum);
  if(lane==0) sm[wid]=ssum;
  __syncthreads();
  float scale = rsqrtf(fmaxf(sm[0]+sm[1]+sm[2]+sm[3],1e-12f));
  for(int d=threadIdx.x; d<DCAT; d+=256)
    pn[(size_t)j*DCAT + d] = cvt_bf16(proxy[(size_t)j*DCAT+d]*scale);
}

__global__ void k_cast(const float* __restrict__ in, short* __restrict__ out, long total){
  long i = (long)blockIdx.x*blockDim.x+threadIdx.x;
  if(i<total) out[i]=cvt_bf16(in[i]);
}

__global__ void k_tcast(const float* __restrict__ in, short* __restrict__ out,
                        int R, int C, int ldo, int coff, float sign){
  __shared__ float tile[32][33];
  int bx = blockIdx.x*32, by = blockIdx.y*32;
  for(int i=threadIdx.y;i<32;i+=8){
    int rr = by+i, cc = bx+threadIdx.x;
    if(rr<R && cc<C) tile[i][threadIdx.x] = in[(size_t)rr*C + cc];
  }
  __syncthreads();
  for(int i=threadIdx.y;i<32;i+=8){
    int cc = bx+i, rr = by+threadIdx.x;
    if(cc<C && rr<R) out[(size_t)cc*ldo + coff + rr] = cvt_bf16(sign*tile[threadIdx.x][i]);
  }
}

// ---------------- generic MFMA GEMM (ring-3, fp32 out) — used for Mx only ----------
template<int LDA_, int LDB_, int NTOT, int KC>
__global__ __launch_bounds__(256,2) void k_gemm(
    const short* __restrict__ A, const short* __restrict__ Bt,
    float* __restrict__ outF, int M)
{
  __shared__ short smem[3][2][128*32];
  const int tid = threadIdx.x;
  const int lane = tid & 63, w = tid >> 6;
  const int wm = w >> 1, wn = w & 1;
  const int bn = blockIdx.x * 128, bm = blockIdx.y * 128;

  const short* Ag = A  + (size_t)bm * LDA_;
  const short* Bg = Bt + (size_t)bn * LDB_;

  auto stage = [&](int buf, int k0){
#pragma unroll
    for(int c=0;c<2;++c){
      int u = c*256 + tid;
      int row = u >> 2;
      int cb = ((u & 3) ^ ((u >> 3) & 3)) * 8;
      __builtin_amdgcn_global_load_lds(
        (const __attribute__((address_space(1))) unsigned int*)(Ag + (size_t)row*LDA_ + k0 + cb),
        (__attribute__((address_space(3))) unsigned int*)&smem[buf][0][u*8], 16, 0, 0);
      __builtin_amdgcn_global_load_lds(
        (const __attribute__((address_space(1))) unsigned int*)(Bg + (size_t)row*LDB_ + k0 + cb),
        (__attribute__((address_space(3))) unsigned int*)&smem[buf][1][u*8], 16, 0, 0);
    }
  };

  f32x4 acc[4][4] = {};
  const int lr = lane & 15, kg = lane >> 4;
  const int ksw = (kg ^ ((lr >> 1) & 3)) * 8;
  constexpr int NT = KC / 32;

  stage(0, 0);
  stage(1, 32);
  for(int t=0; t<NT; ++t){
    if(t+1 < NT) asm volatile("s_waitcnt vmcnt(4)" ::: "memory");
    else         asm volatile("s_waitcnt vmcnt(0)" ::: "memory");
    __builtin_amdgcn_s_barrier();
    __builtin_amdgcn_sched_barrier(0);
    const short* Al = &smem[t%3][0][0];
    const short* Bl = &smem[t%3][1][0];
    bf16x8 af[4], bfr[4];
#pragma unroll
    for(int i=0;i<4;++i) af[i] = *(const bf16x8*)(Al + (wm*64 + i*16 + lr)*32 + ksw);
#pragma unroll
    for(int j=0;j<4;++j) bfr[j] = *(const bf16x8*)(Bl + (wn*64 + j*16 + lr)*32 + ksw);
    if(t+2 < NT) stage((t+2)%3, (t+2)*32);
    __builtin_amdgcn_s_setprio(1);
#pragma unroll
    for(int i=0;i<4;++i)
#pragma unroll
      for(int j=0;j<4;++j)
        acc[i][j] = __builtin_amdgcn_mfma_f32_16x16x32_bf16(af[i], bfr[j], acc[i][j], 0, 0, 0);
    __builtin_amdgcn_s_setprio(0);
  }

  const int row0 = bm + wm*64 + (lane>>4)*4;
  const int col0 = bn + wn*64 + lr;
#pragma unroll
  for(int i=0;i<4;++i)
#pragma unroll
    for(int j=0;j<4;++j)
#pragma unroll
      for(int r=0;r<4;++r){
        int row = row0 + i*16 + r;
        if(row < M) outF[(size_t)row*NTOT + col0 + j*16] = acc[i][j][r];
      }
}

// ---------------- k_pr: proxy-att logits GEMM (K=768) + fused row softmax ---------
__global__ __launch_bounds__(256,2) void k_pr(
    short* __restrict__ Q, const short* __restrict__ pn,
    const float* __restrict__ ssn, int M)
{
  __shared__ short smem[3][2][128*32];
  const int tid = threadIdx.x, lane = tid & 63, w = tid >> 6;
  const int wm = w >> 1, wn = w & 1;
  int nwg = gridDim.y;
  int orig = blockIdx.y;
  int q = nwg>>3, rm = nwg&7, xcd = orig&7, lid = orig>>3;
  int wg = (xcd<rm ? xcd*(q+1) : rm*(q+1)+(xcd-rm)*q) + lid;
  const int bm = wg*128;

  const short* Ag = Q + (size_t)bm * QSTR;
  const short* Bg = pn;

  auto stage = [&](int buf, int k0){
#pragma unroll
    for(int c=0;c<2;++c){
      int u = c*256 + tid;
      int row = u >> 2;
      int cb = ((u & 3) ^ ((u >> 3) & 3)) * 8;
      __builtin_amdgcn_global_load_lds(
        (const __attribute__((address_space(1))) unsigned int*)(Ag + (size_t)row*QSTR + k0 + cb),
        (__attribute__((address_space(3))) unsigned int*)&smem[buf][0][u*8], 16, 0, 0);
      __builtin_amdgcn_global_load_lds(
        (const __attribute__((address_space(1))) unsigned int*)(Bg + (size_t)row*DCAT + k0 + cb),
        (__attribute__((address_space(3))) unsigned int*)&smem[buf][1][u*8], 16, 0, 0);
    }
  };

  f32x4 acc[4][4] = {};
  const int lr = lane & 15, kg = lane >> 4;
  const int ksw = (kg ^ ((lr >> 1) & 3)) * 8;
  constexpr int NT = DCAT / 32;

  stage(0, 0);
  stage(1, 32);
  for(int t=0; t<NT; ++t){
    if(t+1 < NT) asm volatile("s_waitcnt vmcnt(4)" ::: "memory");
    else         asm volatile("s_waitcnt vmcnt(0)" ::: "memory");
    __builtin_amdgcn_s_barrier();
    __builtin_amdgcn_sched_barrier(0);
    const short* Al = &smem[t%3][0][0];
    const short* Bl = &smem[t%3][1][0];
    bf16x8 af[4], bfr[4];
#pragma unroll
    for(int i=0;i<4;++i) af[i] = *(const bf16x8*)(Al + (wm*64 + i*16 + lr)*32 + ksw);
#pragma unroll
    for(int j=0;j<4;++j) bfr[j] = *(const bf16x8*)(Bl + (wn*64 + j*16 + lr)*32 + ksw);
    if(t+2 < NT) stage((t+2)%3, (t+2)*32);
    __builtin_amdgcn_s_setprio(1);
#pragma unroll
    for(int i=0;i<4;++i)
#pragma unroll
      for(int j=0;j<4;++j)
        acc[i][j] = __builtin_amdgcn_mfma_f32_16x16x32_bf16(af[i], bfr[j], acc[i][j], 0, 0, 0);
    __builtin_amdgcn_s_setprio(0);
  }

  // logits -> LDS bf16 [128][132]
  __syncthreads();
  short* lg = (short*)smem;
  const int row0l = wm*64 + kg*4;
  const int col0l = wn*64 + lr;
#pragma unroll
  for(int i=0;i<4;++i){
#pragma unroll
    for(int j=0;j<4;++j){
#pragma unroll
      for(int r=0;r<4;++r){
        int rl = row0l + i*16 + r;
        int rg = bm + rl;
        float s = (rg < M) ? rsqrtf(fmaxf(ssn[rg],1e-12f)) : 0.f;
        lg[rl*132 + col0l + j*16] = cvt_bf16(acc[i][j][r] * s);
      }
    }
  }
  __syncthreads();
  for(int k2=0;k2<32;++k2){
    int rl = w*32 + k2;
    float a = bf2f(lg[rl*132 + lane]);
    float b = bf2f(lg[rl*132 + 64 + lane]);
    float m = waveMax(fmaxf(a,b));
    float ea = __expf(a-m), eb = __expf(b-m);
    float sm_ = waveSum(ea+eb);
    float inv = 1.f/sm_;
    size_t rg = (size_t)(bm + rl);
    Q[rg*QSTR + DCAT + lane]      = cvt_bf16(ea*inv);
    Q[rg*QSTR + DCAT + 64 + lane] = cvt_bf16(eb*inv);
  }
}

// ---------------- k_go: fused gate GEMM + output, 256x128 tile, 8 waves ------------
// main loop: acc = [oc|P] @ BG^T (K=896, ring-3 counted vmcnt, chunk-XOR swizzle)
// then omg = bf16(1-sigmoid(acc)); pv = P @ Bt2^T (K=128 direct global);
// epilogue: out = oc - omg*pv  (coalesced via LDS transpose)
__global__ __launch_bounds__(512,2) void k_go(
    short* __restrict__ Q, const short* __restrict__ BG,
    const short* __restrict__ Bt2, float* __restrict__ outF, int M)
{
  __shared__ short smem[3][384*32];   // per buf: A[256][32] | B[128][32]  (72 KB)
  const int tid = threadIdx.x, lane = tid & 63, w = tid >> 6;   // 8 waves
  const int wm = w >> 1, wn = w & 1;                            // 4x2 wave grid
  const int lr = lane & 15, kg = lane >> 4;
  const int gx = gridDim.x;   // 6
  int nwg = gx*gridDim.y;
  int orig = blockIdx.y*gx + blockIdx.x;
  int q = nwg>>3, rm = nwg&7, xcd = orig&7, lid = orig>>3;
  int wg = (xcd<rm ? xcd*(q+1) : rm*(q+1)+(xcd-rm)*q) + lid;
  const int bn = (wg%gx)*128, bm = (wg/gx)*256;

  const short* Ag = Q  + (size_t)bm * QSTR;
  const short* Bg = BG + (size_t)bn * QSTR;

  auto stage = [&](int buf, int k0){
#pragma unroll
    for(int c=0;c<2;++c){
      int u = c*512 + tid;
      int row = u >> 2;
      int cb = ((u & 3) ^ ((u >> 3) & 3)) * 8;
      __builtin_amdgcn_global_load_lds(
        (const __attribute__((address_space(1))) unsigned int*)(Ag + (size_t)row*QSTR + k0 + cb),
        (__attribute__((address_space(3))) unsigned int*)&smem[buf][u*8], 16, 0, 0);
    }
    {
      int u = tid;
      int row = u >> 2;
      int cb = ((u & 3) ^ ((u >> 3) & 3)) * 8;
      __builtin_amdgcn_global_load_lds(
        (const __attribute__((address_space(1))) unsigned int*)(Bg + (size_t)row*QSTR + k0 + cb),
        (__attribute__((address_space(3))) unsigned int*)&smem[buf][8192 + u*8], 16, 0, 0);
    }
  };

  stage(0, 0);
  stage(1, 32);

  // ---- main loop: gate logits, K=896, ring-3 counted vmcnt (3 loads/stage) ----
  f32x4 acc[4][4] = {};
  const int ksw = (kg ^ ((lr >> 1) & 3)) * 8;
  constexpr int NT = QSTR / 32;   // 28
  for(int t=0; t<NT; ++t){
    if(t+1 < NT) asm volatile("s_waitcnt vmcnt(3)" ::: "memory");
    else         asm volatile("s_waitcnt vmcnt(0)" ::: "memory");
    __builtin_amdgcn_s_barrier();
    __builtin_amdgcn_sched_barrier(0);
    const short* Al = &smem[t%3][0];
    const short* Bl = &smem[t%3][0] + 8192;
    bf16x8 af[4], bfr[4];
#pragma unroll
    for(int i=0;i<4;++i) af[i] = *(const bf16x8*)(Al + (wm*64 + i*16 + lr)*32 + ksw);
#pragma unroll
    for(int j=0;j<4;++j) bfr[j] = *(const bf16x8*)(Bl + (wn*64 + j*16 + lr)*32 + ksw);
    if(t+2 < NT) stage((t+2)%3, (t+2)*32);
    __builtin_amdgcn_s_setprio(1);
#pragma unroll
    for(int i=0;i<4;++i)
#pragma unroll
      for(int j=0;j<4;++j)
        acc[i][j] = __builtin_amdgcn_mfma_f32_16x16x32_bf16(af[i], bfr[j], acc[i][j], 0, 0, 0);
    __builtin_amdgcn_s_setprio(0);
  }

  // ---- omg = bf16(1 - sigmoid(acc)), freeing acc ----
  short4 omg[4][4];
#pragma unroll
  for(int i=0;i<4;++i)
#pragma unroll
    for(int j=0;j<4;++j){
      omg[i][j].x = cvt_bf16(1.f - 1.f/(1.f+__expf(-acc[i][j][0])));
      omg[i][j].y = cvt_bf16(1.f - 1.f/(1.f+__expf(-acc[i][j][1])));
      omg[i][j].z = cvt_bf16(1.f - 1.f/(1.f+__expf(-acc[i][j][2])));
      omg[i][j].w = cvt_bf16(1.f - 1.f/(1.f+__expf(-acc[i][j][3])));
    }

  // ---- pv = P @ Bt2^T (K=128, direct global MFMA) ----
  f32x4 pv[4][4] = {};
#pragma unroll
  for(int ks=0; ks<4; ++ks){
    bf16x8 af2[4];
#pragma unroll
    for(int i=0;i<4;++i)
      af2[i] = *(const bf16x8*)(Q + (size_t)(bm + wm*64 + i*16 + lr)*QSTR + DCAT + ks*32 + kg*8);
#pragma unroll
    for(int j=0;j<4;++j){
      bf16x8 bb = *(const bf16x8*)(Bt2 + (size_t)(bn + wn*64 + j*16 + lr)*NPX + ks*32 + kg*8);
#pragma unroll
      for(int i=0;i<4;++i)
        pv[i][j] = __builtin_amdgcn_mfma_f32_16x16x32_bf16(af2[i], bb, pv[i][j], 0, 0, 0);
    }
  }

  // ---- epilogue: out = oc - omg*pv ----
  __syncthreads();
  short* cst = (short*)smem;   // [256][CSTR]
  const int row0l = wm*64 + kg*4;
  const int col0l = wn*64 + lr;
#pragma unroll
  for(int i=0;i<4;++i)
#pragma unroll
    for(int j=0;j<4;++j){
      float o4[4] = { bf2f(omg[i][j].x), bf2f(omg[i][j].y), bf2f(omg[i][j].z), bf2f(omg[i][j].w) };
#pragma unroll
      for(int r2=0;r2<4;++r2)
        cst[(row0l + i*16 + r2)*CSTR + col0l + j*16] = cvt_bf16(o4[r2]*pv[i][j][r2]);
    }
  __syncthreads();
  const int rl0 = tid>>4, c0 = (tid&15)*8;
#pragma unroll
  for(int rr=0; rr<8; ++rr){
    int rl = rl0 + rr*32;
    int rg = bm + rl;
    if(rg >= M) continue;
    bf16x8 c8  = *(const bf16x8*)(cst + rl*CSTR + c0);
    bf16x8 oc8 = *(const bf16x8*)(Q + (size_t)rg*QSTR + bn + c0);
    float ov[8];
#pragma unroll
    for(int k=0;k<8;k++) ov[k] = bf2f(oc8[k]) - bf2f(c8[k]);
    *(float4*)(outF + (size_t)rg*DCAT + bn + c0)     = make_float4(ov[0],ov[1],ov[2],ov[3]);
    *(float4*)(outF + (size_t)rg*DCAT + bn + c0 + 4) = make_float4(ov[4],ov[5],ov[6],ov[7]);
  }
}

extern "C" void kernel_launch(void* const* d_in, const int* in_sizes, int n_in,
                              void* d_out, int out_size, void* d_ws, size_t ws_size,
                              hipStream_t stream){
  const float* features = (const float*)d_in[0];
  const float* rel_emb  = (const float*)d_in[1];
  const float* p        = (const float*)d_in[2];
  const float* w_keys   = (const float*)d_in[3];
  const float* attn     = (const float*)d_in[4];
  const float* proxy    = (const float*)d_in[5];
  const float* gatek    = (const float*)d_in[6];
  const float* rel_vals = (const float*)d_in[7];
  const int* adj_row    = (const int*)d_in[8];
  const int* adj_col    = (const int*)d_in[9];
  const int* rel_ids    = (const int*)d_in[10];
  const int* new_idx    = (const int*)d_in[11];

  const int n    = in_sizes[2];
  const int r    = in_sizes[1]/D;
  const int e    = in_sizes[7];
  const int ksel = in_sizes[11];
  const size_t Mpad = ((size_t)n + 255) & ~(size_t)255;   // 256-aligned for k_go tile

  char* ws = (char*)d_ws;
  size_t off=0;
  auto alloc=[&](size_t bytes)->void*{ void* pp = ws+off; off=(off+bytes+255)&~(size_t)255; return pp; };
  float* tp      = (float*)alloc((size_t)n*4);
  int*   rs      = (int*)alloc((size_t)(n+1)*4);
  unsigned char* flag = (unsigned char*)alloc((size_t)e);
  float* ss_rel  = (float*)alloc((size_t)r*4);
  float* att_n   = (float*)alloc((size_t)2*r*4);
  float* att_t   = (float*)alloc((size_t)2*r*4);
  short* reb     = (short*)alloc((size_t)r*D*2);
  short* rwb     = (short*)alloc((size_t)2*r*D*2);
  short* pn      = (short*)alloc((size_t)NPX*DCAT*2);
  short* proxyb  = (short*)alloc((size_t)NPX*DCAT*2);
  short* Bt2     = (short*)alloc((size_t)DCAT*NPX*2);
  short* BG      = (short*)alloc((size_t)DCAT*QSTR*2);
  float* MxF     = (float*)alloc((size_t)NPX*DCAT*4);
  float* ssn     = (float*)alloc(Mpad*4);
  short* Q       = (short*)alloc(Mpad*QSTR*2);

  float* outF = (float*)d_out;
  float* pout = (float*)d_out + (size_t)n*DCAT;

  hipMemsetAsync(flag, 0, (size_t)e, stream);
  hipMemsetAsync(Q + (size_t)n*QSTR, 0, (Mpad-(size_t)n)*QSTR*2, stream);

  int prep_n = (ksel > n+1 ? ksel : n+1);
  k_prep<<<(prep_n+255)/256,256,0,stream>>>(p,tp,adj_row,rs,new_idx,flag,pout,n,e,ksel);
  k_relprep<<<r,256,0,stream>>>(rel_emb,attn,ss_rel,att_n,reb,r);
  for(int l=0;l<2;l++)
    k_relW<<<r,256,0,stream>>>(rel_emb, w_keys+(size_t)l*D*D, attn+(size_t)l*D,
                               rwb+(size_t)l*r*D, att_t+(size_t)l*r, r);
  k_proxynorm<<<NPX,256,0,stream>>>(proxy,pn);
  {
    long tpx = (long)NPX*DCAT;
    k_cast<<<(int)((tpx+255)/256),256,0,stream>>>(proxy, proxyb, tpx);
    dim3 tb(32,8);
    k_tcast<<<dim3(DCAT/32, DCAT/32), tb, 0, stream>>>(gatek, BG, DCAT, DCAT, QSTR, 0, 1.f);
    k_gemm<DCAT, QSTR, DCAT, DCAT><<<dim3(DCAT/128,1),256,0,stream>>>(proxyb, BG, MxF, NPX);
    k_tcast<<<dim3(DCAT/32, NPX/32), tb, 0, stream>>>(MxF, BG, NPX, DCAT, QSTR, DCAT, -1.f);
    k_tcast<<<dim3(DCAT/32, NPX/32), tb, 0, stream>>>(proxy, Bt2, NPX, DCAT, NPX, 0, 1.f);
  }
  k_init0<<<n,256,0,stream>>>(features,tp,Q,ssn,n);
  for(int l=0;l<2;l++)
    k_agg<<<(n+3)/4,256,0,stream>>>(rs,adj_col,rel_ids,rel_vals,flag,tp,ss_rel,
                                    att_n+(size_t)l*r, att_t+(size_t)l*r, reb,
                                    rwb+(size_t)l*r*D, Q, ssn, n, l);

  // k_pr: proxy-att logits + fused l2n + softmax -> probs into Q[:,768:896]
  k_pr<<<dim3(1, (int)(Mpad/128)),256,0,stream>>>(Q, pn, ssn, n);
  // k_go: 256x128-tile fused gate + output
  k_go<<<dim3(DCAT/128, (int)(Mpad/256)),512,0,stream>>>(Q, BG, Bt2, outF, n);
}

// Round 13
// 444.324 us; speedup vs baseline: 1.1795x; 1.1376x over previous
//
#include <hip/hip_runtime.h>
#include <math.h>

#define D 256
#define DCAT 768
#define NPX 128
#define QSTR 896   // Q row stride: [outcat(768) | P(128)] bf16
#define CSTR 136   // padded LDS row stride (shorts) for epilogue transpose

typedef __attribute__((ext_vector_type(8))) short bf16x8;
typedef __attribute__((ext_vector_type(4))) float f32x4;

__device__ __forceinline__ short cvt_bf16(float f){
  union { float f; unsigned u; } v; v.f = f;
  unsigned r = v.u + 0x7FFF + ((v.u >> 16) & 1);   // RNE
  return (short)(r >> 16);
}
__device__ __forceinline__ float bf2f(short s){
  union { float f; unsigned u; } v; v.u = ((unsigned)(unsigned short)s) << 16;
  return v.f;
}

__device__ __forceinline__ float waveSum(float v){
#pragma unroll
  for(int o=32;o>=1;o>>=1) v += __shfl_xor(v,o,64);
  return v;
}
__device__ __forceinline__ float waveMax(float v){
#pragma unroll
  for(int o=32;o>=1;o>>=1) v = fmaxf(v,__shfl_xor(v,o,64));
  return v;
}

// merged: tanh(p), rowstart binary search, new_indices flag, p copy to output
__global__ void k_prep(const float* __restrict__ p, float* __restrict__ tp,
                       const int* __restrict__ adj_row, int* __restrict__ rs,
                       const int* __restrict__ idx, unsigned char* __restrict__ flag,
                       float* __restrict__ pout, int n, int e, int ksel){
  int i = blockIdx.x*blockDim.x+threadIdx.x;
  if(i<n){ float pv = p[i]; tp[i]=tanhf(pv); pout[i]=pv; }
  if(i<=n){
    int lo=0, hi=e;
    while(lo<hi){ int mid=(lo+hi)>>1; if(adj_row[mid]<i) lo=mid+1; else hi=mid; }
    rs[i]=lo;
  }
  if(i<ksel) flag[idx[i]] = 1;
}

// merged setup: blocks [0,R): relprep | [R,3R): relW l=0/1 | [3R,3R+128): proxy norm+cast
// | next 576: gk tcast -> BG | next 96: proxy tcast -> Bt2
__global__ void k_setup(const float* __restrict__ rel_emb, const float* __restrict__ attn,
                        const float* __restrict__ w_keys, const float* __restrict__ proxy,
                        const float* __restrict__ gatek,
                        float* __restrict__ ss_rel, float* __restrict__ att_n,
                        float* __restrict__ att_t, short* __restrict__ reb,
                        short* __restrict__ rwb, short* __restrict__ pn,
                        short* __restrict__ proxyb, short* __restrict__ BG,
                        short* __restrict__ Bt2, int R_){
  __shared__ float tile[32][33];
  __shared__ float sm[4];
  const int b = blockIdx.x, tid = threadIdx.x;
  const int lane = tid & 63, wv = tid >> 6;

  if(b < R_){
    // ---- relprep ----
    int r = b, d = tid;
    float v = rel_emb[(size_t)r*D+d];
    reb[(size_t)r*D+d] = cvt_bf16(v);
    float s = waveSum(v*v);
    if(lane==0) sm[wv]=s;
    __syncthreads();
    if(tid==0) ss_rel[r]=sm[0]+sm[1]+sm[2]+sm[3];
    __syncthreads();
    for(int l=0;l<2;l++){
      float dd = waveSum(v*attn[l*D+d]);
      if(lane==0) sm[wv]=dd;
      __syncthreads();
      if(tid==0) att_n[(size_t)l*R_+r]=sm[0]+sm[1]+sm[2]+sm[3];
      __syncthreads();
    }
  } else if(b < 3*R_){
    // ---- relW ----
    int l = (b-R_) / R_, r = (b-R_) % R_, d = tid;
    const float* W = w_keys + (size_t)l*D*D;
    const float* ak = attn + (size_t)l*D;
    const float* row = rel_emb + (size_t)r*D;
    float acc=0.f;
#pragma unroll 4
    for(int k=0;k<D;k++) acc = fmaf(row[k], W[(size_t)k*D+d], acc);
    rwb[(size_t)l*R_*D + (size_t)r*D + d]=cvt_bf16(acc);
    float dd = waveSum(acc*ak[d]);
    if(lane==0) sm[wv]=dd;
    __syncthreads();
    if(tid==0) att_t[(size_t)l*R_+r]=sm[0]+sm[1]+sm[2]+sm[3];
  } else if(b < 3*R_+128){
    // ---- proxy: l2-normalized pn + plain bf16 cast proxyb ----
    int j = b - 3*R_;
    float v0 = proxy[(size_t)j*DCAT + tid];
    float v1 = proxy[(size_t)j*DCAT + 256 + tid];
    float v2 = proxy[(size_t)j*DCAT + 512 + tid];
    proxyb[(size_t)j*DCAT + tid]       = cvt_bf16(v0);
    proxyb[(size_t)j*DCAT + 256 + tid] = cvt_bf16(v1);
    proxyb[(size_t)j*DCAT + 512 + tid] = cvt_bf16(v2);
    float ssum = waveSum(v0*v0 + v1*v1 + v2*v2);
    if(lane==0) sm[wv]=ssum;
    __syncthreads();
    float scale = rsqrtf(fmaxf(sm[0]+sm[1]+sm[2]+sm[3],1e-12f));
    pn[(size_t)j*DCAT + tid]       = cvt_bf16(v0*scale);
    pn[(size_t)j*DCAT + 256 + tid] = cvt_bf16(v1*scale);
    pn[(size_t)j*DCAT + 512 + tid] = cvt_bf16(v2*scale);
  } else {
    // ---- transpose-cast tiles ----
    const float* in; short* out; int R, C, ldo, coff, t;
    if(b < 3*R_+128+576){ t = b-(3*R_+128);     in=gatek; out=BG;  R=DCAT; C=DCAT; ldo=QSTR; coff=0; }
    else                { t = b-(3*R_+128+576); in=proxy; out=Bt2; R=NPX;  C=DCAT; ldo=NPX;  coff=0; }
    int bx = (t%24)*32, by = (t/24)*32;
    int tx = tid & 31, ty = tid >> 5;
    for(int i=ty;i<32;i+=8){
      int rr = by+i, cc = bx+tx;
      if(rr<R && cc<C) tile[i][tx] = in[(size_t)rr*C + cc];
    }
    __syncthreads();
    for(int i=ty;i<32;i+=8){
      int cc = bx+i, rr = by+tx;
      if(cc<C && rr<R) out[(size_t)cc*ldo + coff + rr] = cvt_bf16(tile[tx][i]);
    }
  }
}

// transpose-cast (standalone, for MxTn after k_gemm)
__global__ void k_tcast(const float* __restrict__ in, short* __restrict__ out,
                        int R, int C, int ldo, int coff, float sign){
  __shared__ float tile[32][33];
  int bx = blockIdx.x*32, by = blockIdx.y*32;
  for(int i=threadIdx.y;i<32;i+=8){
    int rr = by+i, cc = bx+threadIdx.x;
    if(rr<R && cc<C) tile[i][threadIdx.x] = in[(size_t)rr*C + cc];
  }
  __syncthreads();
  for(int i=threadIdx.y;i<32;i+=8){
    int cc = bx+i, rr = by+threadIdx.x;
    if(cc<C && rr<R) out[(size_t)cc*ldo + coff + rr] = cvt_bf16(sign*tile[threadIdx.x][i]);
  }
}

// one block per row: write Q cols 0..255 and init ssn[row] = sum of squares
__global__ void k_init0(const float* __restrict__ features, const float* __restrict__ tp,
                        short* __restrict__ Q, float* __restrict__ ssn, int n){
  __shared__ float sm[4];
  int row = blockIdx.x, d = threadIdx.x;
  float v = features[(size_t)row*D + d] * tp[row];
  Q[(size_t)row*QSTR + d] = cvt_bf16(v);
  int lane=d&63, wid=d>>6;
  float s = waveSum(v*v);
  if(lane==0) sm[wid]=s;
  __syncthreads();
  if(d==0) ssn[row] = sm[0]+sm[1]+sm[2]+sm[3];
}

// one wave per node; fused single logit pass (bit-exact) + metadata-prefetched
// main loop (R9-exact arithmetic, loads only moved)
__global__ void k_agg(const int* __restrict__ rs, const int* __restrict__ adj_col,
                      const int* __restrict__ rel_ids, const float* __restrict__ rel_vals,
                      const unsigned char* __restrict__ flag, const float* __restrict__ tp,
                      const float* __restrict__ ss_rel, const float* __restrict__ att_n,
                      const float* __restrict__ att_t, const short* __restrict__ reb,
                      const short* __restrict__ rwb, short* __restrict__ Q,
                      float* __restrict__ ssn, int n, int layer){
  int wid = threadIdx.x>>6, lane = threadIdx.x&63;
  int node = blockIdx.x*4 + wid;
  if(node>=n) return;
  int s = rs[node], e = rs[node+1];
  float accq[16];
#pragma unroll
  for(int k=0;k<16;k++) accq[k]=0.f;

  auto logit = [&](int i)->float{
    int rid = rel_ids[i]; float rv = rel_vals[i];
    float a = 0.f;
    if(rv>0.f){
      float t = tp[adj_col[i]];
      float sc = rv*rsqrtf(fmaxf(rv*rv*ss_rel[rid],1e-12f));
      a = t*sc*(flag[i]? att_t[rid] : att_n[rid]);
    }
    return a;
  };

  if(e > s){
    // single logit pass: per-lane aF (edge s+lane) + strided max
    float aF = 0.f, mxl = -INFINITY;
    {
      int i = s + lane;
      if(i < e){
        aF = logit(i);
        mxl = aF;
        for(i += 64; i < e; i += 64) mxl = fmaxf(mxl, logit(i));
      }
    }
    float mx = waveMax(mxl);
    float sel = (s+lane < e) ? __expf(aF - mx) : 0.f;
    for(int i = s+64+lane; i < e; i += 64) sel += __expf(logit(i) - mx);
    float se = waveSum(sel);
    float inv = 1.f/se;

    int qid = lane>>4, ql = lane&15;
    // prefetch metadata for first group
    int j0 = s + qid;
    bool valid = j0 < e;
    int col=0, rid=0; float rv=0.f; bool fl=false;
    if(valid){ col=adj_col[j0]; rid=rel_ids[j0]; rv=rel_vals[j0]; fl=flag[j0]; }
    for(int i0=s; i0<e; i0+=4){
      // prefetch next group's metadata (loads only — arithmetic order unchanged)
      int jn = i0 + 4 + qid;
      bool vn = jn < e;
      int coln=0, ridn=0; float rvn=0.f; bool fln=false;
      if(vn){ coln=adj_col[jn]; ridn=rel_ids[jn]; rvn=rel_vals[jn]; fln=flag[jn]; }

      float w=0.f, coef=0.f;
      float nbv[16], rbv[16];
#pragma unroll
      for(int k=0;k<16;k++){ nbv[k]=0.f; rbv[k]=0.f; }
      if(valid){
        const short* np = Q + (size_t)col*QSTR + layer*D + ql*16;
        bf16x8 n0 = *(const bf16x8*)np;
        bf16x8 n1 = *(const bf16x8*)(np+8);
#pragma unroll
        for(int k=0;k<8;k++){ nbv[k]=bf2f(n0[k]); nbv[k+8]=bf2f(n1[k]); }
        if(rv>0.f){
          float t = tp[col];
          float sc = rv*rsqrtf(fmaxf(rv*rv*ss_rel[rid],1e-12f));
          const short* rp = (fl? rwb : reb) + (size_t)rid*D + ql*16;
          bf16x8 r0 = *(const bf16x8*)rp;
          bf16x8 r1 = *(const bf16x8*)(rp+8);
#pragma unroll
          for(int k=0;k<8;k++){ rbv[k]=bf2f(r0[k]); rbv[k+8]=bf2f(r1[k]); }
          float dp = 0.f;
#pragma unroll
          for(int k=0;k<16;k++) dp += nbv[k]*rbv[k];
#pragma unroll
          for(int o=1;o<16;o<<=1) dp += __shfl_xor(dp,o,64);
          float a = t*sc*(fl? att_t[rid] : att_n[rid]);
          w = __expf(a-mx)*inv;
          coef = 2.f*t*t*sc*sc*dp;
        } else {
          w = __expf(-mx)*inv;
        }
      }
#pragma unroll
      for(int k=0;k<16;k++) accq[k] += w*(nbv[k] - coef*rbv[k]);

      valid=vn; col=coln; rid=ridn; rv=rvn; fl=fln;
    }
  }
#pragma unroll
  for(int k=0;k<16;k++){
    float v = accq[k];
    v += __shfl_xor(v,16,64);
    v += __shfl_xor(v,32,64);
    accq[k] = v;
  }
  if(lane < 16){
    float t0 = tp[node];
    bf16x8 o0, o1;
    float pss = 0.f;
#pragma unroll
    for(int k=0;k<8;k++){
      o0[k]=cvt_bf16(accq[k]*t0); o1[k]=cvt_bf16(accq[k+8]*t0);
      pss += accq[k]*accq[k] + accq[k+8]*accq[k+8];
    }
    short* op = Q + (size_t)node*QSTR + (layer+1)*D + lane*16;
    *(bf16x8*)op = o0;
    *(bf16x8*)(op+8) = o1;
#pragma unroll
    for(int o=1;o<16;o<<=1) pss += __shfl_xor(pss,o,64);
    if(lane==0) ssn[node] += pss * t0 * t0;
  }
}

// ---------------- generic MFMA GEMM (ring-3, fp32 out) — used for Mx only ----------
template<int LDA_, int LDB_, int NTOT, int KC>
__global__ __launch_bounds__(256,2) void k_gemm(
    const short* __restrict__ A, const short* __restrict__ Bt,
    float* __restrict__ outF, int M)
{
  __shared__ short smem[3][2][128*32];
  const int tid = threadIdx.x;
  const int lane = tid & 63, w = tid >> 6;
  const int wm = w >> 1, wn = w & 1;
  const int bn = blockIdx.x * 128, bm = blockIdx.y * 128;

  const short* Ag = A  + (size_t)bm * LDA_;
  const short* Bg = Bt + (size_t)bn * LDB_;

  auto stage = [&](int buf, int k0){
#pragma unroll
    for(int c=0;c<2;++c){
      int u = c*256 + tid;
      int row = u >> 2;
      int cb = ((u & 3) ^ ((u >> 3) & 3)) * 8;
      __builtin_amdgcn_global_load_lds(
        (const __attribute__((address_space(1))) unsigned int*)(Ag + (size_t)row*LDA_ + k0 + cb),
        (__attribute__((address_space(3))) unsigned int*)&smem[buf][0][u*8], 16, 0, 0);
      __builtin_amdgcn_global_load_lds(
        (const __attribute__((address_space(1))) unsigned int*)(Bg + (size_t)row*LDB_ + k0 + cb),
        (__attribute__((address_space(3))) unsigned int*)&smem[buf][1][u*8], 16, 0, 0);
    }
  };

  f32x4 acc[4][4] = {};
  const int lr = lane & 15, kg = lane >> 4;
  const int ksw = (kg ^ ((lr >> 1) & 3)) * 8;
  constexpr int NT = KC / 32;

  stage(0, 0);
  stage(1, 32);
  for(int t=0; t<NT; ++t){
    if(t+1 < NT) asm volatile("s_waitcnt vmcnt(4)" ::: "memory");
    else         asm volatile("s_waitcnt vmcnt(0)" ::: "memory");
    __builtin_amdgcn_s_barrier();
    __builtin_amdgcn_sched_barrier(0);
    const short* Al = &smem[t%3][0][0];
    const short* Bl = &smem[t%3][1][0];
    bf16x8 af[4], bfr[4];
#pragma unroll
    for(int i=0;i<4;++i) af[i] = *(const bf16x8*)(Al + (wm*64 + i*16 + lr)*32 + ksw);
#pragma unroll
    for(int j=0;j<4;++j) bfr[j] = *(const bf16x8*)(Bl + (wn*64 + j*16 + lr)*32 + ksw);
    if(t+2 < NT) stage((t+2)%3, (t+2)*32);
    __builtin_amdgcn_s_setprio(1);
#pragma unroll
    for(int i=0;i<4;++i)
#pragma unroll
      for(int j=0;j<4;++j)
        acc[i][j] = __builtin_amdgcn_mfma_f32_16x16x32_bf16(af[i], bfr[j], acc[i][j], 0, 0, 0);
    __builtin_amdgcn_s_setprio(0);
  }

  const int row0 = bm + wm*64 + (lane>>4)*4;
  const int col0 = bn + wn*64 + lr;
#pragma unroll
  for(int i=0;i<4;++i)
#pragma unroll
    for(int j=0;j<4;++j)
#pragma unroll
      for(int r=0;r<4;++r){
        int row = row0 + i*16 + r;
        if(row < M) outF[(size_t)row*NTOT + col0 + j*16] = acc[i][j][r];
      }
}

// ---------------- k_pr: proxy-att logits GEMM (K=768) + fused row softmax ---------
__global__ __launch_bounds__(256,2) void k_pr(
    short* __restrict__ Q, const short* __restrict__ pn,
    const float* __restrict__ ssn, int M)
{
  __shared__ short smem[3][2][128*32];
  const int tid = threadIdx.x, lane = tid & 63, w = tid >> 6;
  const int wm = w >> 1, wn = w & 1;
  int nwg = gridDim.y;
  int orig = blockIdx.y;
  int q = nwg>>3, rm = nwg&7, xcd = orig&7, lid = orig>>3;
  int wg = (xcd<rm ? xcd*(q+1) : rm*(q+1)+(xcd-rm)*q) + lid;
  const int bm = wg*128;

  const short* Ag = Q + (size_t)bm * QSTR;
  const short* Bg = pn;

  auto stage = [&](int buf, int k0){
#pragma unroll
    for(int c=0;c<2;++c){
      int u = c*256 + tid;
      int row = u >> 2;
      int cb = ((u & 3) ^ ((u >> 3) & 3)) * 8;
      __builtin_amdgcn_global_load_lds(
        (const __attribute__((address_space(1))) unsigned int*)(Ag + (size_t)row*QSTR + k0 + cb),
        (__attribute__((address_space(3))) unsigned int*)&smem[buf][0][u*8], 16, 0, 0);
      __builtin_amdgcn_global_load_lds(
        (const __attribute__((address_space(1))) unsigned int*)(Bg + (size_t)row*DCAT + k0 + cb),
        (__attribute__((address_space(3))) unsigned int*)&smem[buf][1][u*8], 16, 0, 0);
    }
  };

  f32x4 acc[4][4] = {};
  const int lr = lane & 15, kg = lane >> 4;
  const int ksw = (kg ^ ((lr >> 1) & 3)) * 8;
  constexpr int NT = DCAT / 32;

  stage(0, 0);
  stage(1, 32);
  for(int t=0; t<NT; ++t){
    if(t+1 < NT) asm volatile("s_waitcnt vmcnt(4)" ::: "memory");
    else         asm volatile("s_waitcnt vmcnt(0)" ::: "memory");
    __builtin_amdgcn_s_barrier();
    __builtin_amdgcn_sched_barrier(0);
    const short* Al = &smem[t%3][0][0];
    const short* Bl = &smem[t%3][1][0];
    bf16x8 af[4], bfr[4];
#pragma unroll
    for(int i=0;i<4;++i) af[i] = *(const bf16x8*)(Al + (wm*64 + i*16 + lr)*32 + ksw);
#pragma unroll
    for(int j=0;j<4;++j) bfr[j] = *(const bf16x8*)(Bl + (wn*64 + j*16 + lr)*32 + ksw);
    if(t+2 < NT) stage((t+2)%3, (t+2)*32);
    __builtin_amdgcn_s_setprio(1);
#pragma unroll
    for(int i=0;i<4;++i)
#pragma unroll
      for(int j=0;j<4;++j)
        acc[i][j] = __builtin_amdgcn_mfma_f32_16x16x32_bf16(af[i], bfr[j], acc[i][j], 0, 0, 0);
    __builtin_amdgcn_s_setprio(0);
  }

  // logits -> LDS bf16 [128][132]
  __syncthreads();
  short* lg = (short*)smem;
  const int row0l = wm*64 + kg*4;
  const int col0l = wn*64 + lr;
#pragma unroll
  for(int i=0;i<4;++i){
#pragma unroll
    for(int j=0;j<4;++j){
#pragma unroll
      for(int r=0;r<4;++r){
        int rl = row0l + i*16 + r;
        int rg = bm + rl;
        float s = (rg < M) ? rsqrtf(fmaxf(ssn[rg],1e-12f)) : 0.f;
        lg[rl*132 + col0l + j*16] = cvt_bf16(acc[i][j][r] * s);
      }
    }
  }
  __syncthreads();
  for(int k2=0;k2<32;++k2){
    int rl = w*32 + k2;
    float a = bf2f(lg[rl*132 + lane]);
    float b = bf2f(lg[rl*132 + 64 + lane]);
    float m = waveMax(fmaxf(a,b));
    float ea = __expf(a-m), eb = __expf(b-m);
    float sm_ = waveSum(ea+eb);
    float inv = 1.f/sm_;
    size_t rg = (size_t)(bm + rl);
    Q[rg*QSTR + DCAT + lane]      = cvt_bf16(ea*inv);
    Q[rg*QSTR + DCAT + 64 + lane] = cvt_bf16(eb*inv);
  }
}

// ---------------- k_go: fused gate GEMM + output (R9-exact 128² ring-3) ------------
__global__ __launch_bounds__(256,2) void k_go(
    short* __restrict__ Q, const short* __restrict__ BG,
    const short* __restrict__ Bt2, float* __restrict__ outF, int M)
{
  __shared__ short smem[3][2][128*32];
  const int tid = threadIdx.x, lane = tid & 63, w = tid >> 6;
  const int wm = w >> 1, wn = w & 1;
  const int gx = gridDim.x;
  int nwg = gx*gridDim.y;
  int orig = blockIdx.y*gx + blockIdx.x;
  int q = nwg>>3, rm = nwg&7, xcd = orig&7, lid = orig>>3;
  int wg = (xcd<rm ? xcd*(q+1) : rm*(q+1)+(xcd-rm)*q) + lid;
  const int bn = (wg%gx)*128, bm = (wg/gx)*128;
  const int lr = lane & 15, kg = lane >> 4;

  const short* Ag = Q  + (size_t)bm * QSTR;
  const short* Bg = BG + (size_t)bn * QSTR;

  auto stage = [&](int buf, int k0){
#pragma unroll
    for(int c=0;c<2;++c){
      int u = c*256 + tid;
      int row = u >> 2;
      int cb = ((u & 3) ^ ((u >> 3) & 3)) * 8;
      __builtin_amdgcn_global_load_lds(
        (const __attribute__((address_space(1))) unsigned int*)(Ag + (size_t)row*QSTR + k0 + cb),
        (__attribute__((address_space(3))) unsigned int*)&smem[buf][0][u*8], 16, 0, 0);
      __builtin_amdgcn_global_load_lds(
        (const __attribute__((address_space(1))) unsigned int*)(Bg + (size_t)row*QSTR + k0 + cb),
        (__attribute__((address_space(3))) unsigned int*)&smem[buf][1][u*8], 16, 0, 0);
    }
  };

  stage(0, 0);
  stage(1, 32);

  // ---- phase A: pv = P @ Bt2^T (K=128, direct global MFMA) ----
  f32x4 acc[4][4] = {};
#pragma unroll
  for(int ks=0; ks<4; ++ks){
    bf16x8 af[4], bb[4];
#pragma unroll
    for(int i=0;i<4;++i)
      af[i] = *(const bf16x8*)(Q + (size_t)(bm + wm*64 + i*16 + lr)*QSTR + DCAT + ks*32 + kg*8);
#pragma unroll
    for(int j=0;j<4;++j)
      bb[j] = *(const bf16x8*)(Bt2 + (size_t)(bn + wn*64 + j*16 + lr)*NPX + ks*32 + kg*8);
#pragma unroll
    for(int i=0;i<4;++i)
#pragma unroll
      for(int j=0;j<4;++j)
        acc[i][j] = __builtin_amdgcn_mfma_f32_16x16x32_bf16(af[i], bb[j], acc[i][j], 0, 0, 0);
  }
  short4 pvb[4][4];
#pragma unroll
  for(int i=0;i<4;++i)
#pragma unroll
    for(int j=0;j<4;++j){
      pvb[i][j].x = cvt_bf16(acc[i][j][0]);
      pvb[i][j].y = cvt_bf16(acc[i][j][1]);
      pvb[i][j].z = cvt_bf16(acc[i][j][2]);
      pvb[i][j].w = cvt_bf16(acc[i][j][3]);
      acc[i][j] = (f32x4){0.f,0.f,0.f,0.f};
    }

  // ---- main loop: gate logits, K=896, ring-3 counted vmcnt ----
  const int ksw = (kg ^ ((lr >> 1) & 3)) * 8;
  constexpr int NT = QSTR / 32;   // 28
  for(int t=0; t<NT; ++t){
    if(t+1 < NT) asm volatile("s_waitcnt vmcnt(4)" ::: "memory");
    else         asm volatile("s_waitcnt vmcnt(0)" ::: "memory");
    __builtin_amdgcn_s_barrier();
    __builtin_amdgcn_sched_barrier(0);
    const short* Al = &smem[t%3][0][0];
    const short* Bl = &smem[t%3][1][0];
    bf16x8 af[4], bfr[4];
#pragma unroll
    for(int i=0;i<4;++i) af[i] = *(const bf16x8*)(Al + (wm*64 + i*16 + lr)*32 + ksw);
#pragma unroll
    for(int j=0;j<4;++j) bfr[j] = *(const bf16x8*)(Bl + (wn*64 + j*16 + lr)*32 + ksw);
    if(t+2 < NT) stage((t+2)%3, (t+2)*32);
    __builtin_amdgcn_s_setprio(1);
#pragma unroll
    for(int i=0;i<4;++i)
#pragma unroll
      for(int j=0;j<4;++j)
        acc[i][j] = __builtin_amdgcn_mfma_f32_16x16x32_bf16(af[i], bfr[j], acc[i][j], 0, 0, 0);
    __builtin_amdgcn_s_setprio(0);
  }

  // ---- epilogue: out = oc - (1-g)*pv ----
  __syncthreads();
  short* cst = (short*)smem;
  const int row0l = wm*64 + kg*4;
  const int col0l = wn*64 + lr;
#pragma unroll
  for(int i=0;i<4;++i){
#pragma unroll
    for(int j=0;j<4;++j){
      float pv4[4] = { bf2f(pvb[i][j].x), bf2f(pvb[i][j].y), bf2f(pvb[i][j].z), bf2f(pvb[i][j].w) };
#pragma unroll
      for(int r2=0;r2<4;++r2){
        float g = 1.f/(1.f+__expf(-acc[i][j][r2]));
        cst[(row0l + i*16 + r2)*CSTR + col0l + j*16] = cvt_bf16((1.f-g)*pv4[r2]);
      }
    }
  }
  __syncthreads();
  const int rl0 = tid>>4, c0 = (tid&15)*8;
#pragma unroll
  for(int rr=0; rr<8; ++rr){
    int rl = rl0 + rr*16;
    int rg = bm + rl;
    if(rg >= M) continue;
    bf16x8 c8  = *(const bf16x8*)(cst + rl*CSTR + c0);
    bf16x8 oc8 = *(const bf16x8*)(Q + (size_t)rg*QSTR + bn + c0);
    float ov[8];
#pragma unroll
    for(int k=0;k<8;k++) ov[k] = bf2f(oc8[k]) - bf2f(c8[k]);
    *(float4*)(outF + (size_t)rg*DCAT + bn + c0)     = make_float4(ov[0],ov[1],ov[2],ov[3]);
    *(float4*)(outF + (size_t)rg*DCAT + bn + c0 + 4) = make_float4(ov[4],ov[5],ov[6],ov[7]);
  }
}

extern "C" void kernel_launch(void* const* d_in, const int* in_sizes, int n_in,
                              void* d_out, int out_size, void* d_ws, size_t ws_size,
                              hipStream_t stream){
  const float* features = (const float*)d_in[0];
  const float* rel_emb  = (const float*)d_in[1];
  const float* p        = (const float*)d_in[2];
  const float* w_keys   = (const float*)d_in[3];
  const float* attn     = (const float*)d_in[4];
  const float* proxy    = (const float*)d_in[5];
  const float* gatek    = (const float*)d_in[6];
  const float* rel_vals = (const float*)d_in[7];
  const int* adj_row    = (const int*)d_in[8];
  const int* adj_col    = (const int*)d_in[9];
  const int* rel_ids    = (const int*)d_in[10];
  const int* new_idx    = (const int*)d_in[11];

  const int n    = in_sizes[2];
  const int r    = in_sizes[1]/D;
  const int e    = in_sizes[7];
  const int ksel = in_sizes[11];
  const size_t Mpad = ((size_t)n + 127) & ~(size_t)127;

  char* ws = (char*)d_ws;
  size_t off=0;
  auto alloc=[&](size_t bytes)->void*{ void* pp = ws+off; off=(off+bytes+255)&~(size_t)255; return pp; };
  float* tp      = (float*)alloc((size_t)n*4);
  int*   rs      = (int*)alloc((size_t)(n+1)*4);
  unsigned char* flag = (unsigned char*)alloc((size_t)e);
  float* ss_rel  = (float*)alloc((size_t)r*4);
  float* att_n   = (float*)alloc((size_t)2*r*4);
  float* att_t   = (float*)alloc((size_t)2*r*4);
  short* reb     = (short*)alloc((size_t)r*D*2);
  short* rwb     = (short*)alloc((size_t)2*r*D*2);
  short* pn      = (short*)alloc((size_t)NPX*DCAT*2);
  short* proxyb  = (short*)alloc((size_t)NPX*DCAT*2);
  short* Bt2     = (short*)alloc((size_t)DCAT*NPX*2);
  short* BG      = (short*)alloc((size_t)DCAT*QSTR*2);
  float* MxF     = (float*)alloc((size_t)NPX*DCAT*4);
  float* ssn     = (float*)alloc(Mpad*4);
  short* Q       = (short*)alloc(Mpad*QSTR*2);

  float* outF = (float*)d_out;
  float* pout = (float*)d_out + (size_t)n*DCAT;

  hipMemsetAsync(flag, 0, (size_t)e, stream);
  hipMemsetAsync(Q + (size_t)n*QSTR, 0, (Mpad-(size_t)n)*QSTR*2, stream);

  int prep_n = (ksel > n+1 ? ksel : n+1);
  k_prep<<<(prep_n+255)/256,256,0,stream>>>(p,tp,adj_row,rs,new_idx,flag,pout,n,e,ksel);
  // merged setup: relprep + relW(l=0,1) + proxy(norm+cast) + gk tcast + Bt2 tcast
  {
    int nblocks = 3*r + 128 + 576 + 96;
    k_setup<<<nblocks,256,0,stream>>>(rel_emb, attn, w_keys, proxy, gatek,
                                      ss_rel, att_n, att_t, reb, rwb, pn, proxyb,
                                      BG, Bt2, r);
  }
  // Mx = proxy @ gk, then -Mx^T into BG cols 768..895
  k_gemm<DCAT, QSTR, DCAT, DCAT><<<dim3(DCAT/128,1),256,0,stream>>>(proxyb, BG, MxF, NPX);
  k_tcast<<<dim3(DCAT/32, NPX/32), dim3(32,8), 0, stream>>>(MxF, BG, NPX, DCAT, QSTR, DCAT, -1.f);

  k_init0<<<n,256,0,stream>>>(features,tp,Q,ssn,n);
  for(int l=0;l<2;l++)
    k_agg<<<(n+3)/4,256,0,stream>>>(rs,adj_col,rel_ids,rel_vals,flag,tp,ss_rel,
                                    att_n+(size_t)l*r, att_t+(size_t)l*r, reb,
                                    rwb+(size_t)l*r*D, Q, ssn, n, l);

  int mt = (int)(Mpad/128);
  // k_pr: proxy-att logits + fused l2n + softmax -> probs into Q[:,768:896]
  k_pr<<<dim3(1, mt),256,0,stream>>>(Q, pn, ssn, n);
  // k_go: fused gate + output
  k_go<<<dim3(DCAT/128, mt),256,0,stream>>>(Q, BG, Bt2, outF, n);
}

// Round 14
// 434.241 us; speedup vs baseline: 1.2069x; 1.0232x over previous
//
#include <hip/hip_runtime.h>
#include <math.h>

#define D 256
#define DCAT 768
#define NPX 128
#define QSTR 896   // Q row stride: [outcat(768) | P(128)] bf16
#define CSTR 136   // padded LDS row stride (shorts) for epilogue transpose

typedef __attribute__((ext_vector_type(8))) short bf16x8;
typedef __attribute__((ext_vector_type(4))) float f32x4;

__device__ __forceinline__ short cvt_bf16(float f){
  union { float f; unsigned u; } v; v.f = f;
  unsigned r = v.u + 0x7FFF + ((v.u >> 16) & 1);   // RNE
  return (short)(r >> 16);
}
__device__ __forceinline__ float bf2f(short s){
  union { float f; unsigned u; } v; v.u = ((unsigned)(unsigned short)s) << 16;
  return v.f;
}

__device__ __forceinline__ float waveSum(float v){
#pragma unroll
  for(int o=32;o>=1;o>>=1) v += __shfl_xor(v,o,64);
  return v;
}
__device__ __forceinline__ float waveMax(float v){
#pragma unroll
  for(int o=32;o>=1;o>>=1) v = fmaxf(v,__shfl_xor(v,o,64));
  return v;
}

// merged setup: [0,R): relprep | [R,3R): relW l=0/1 | [3R,3R+128): proxy norm+cast
// | +576: gk tcast -> BG | +96: proxy tcast -> Bt2 | rest: prep (tanh/rowstart/flag/pout)
__global__ void k_setup(const float* __restrict__ rel_emb, const float* __restrict__ attn,
                        const float* __restrict__ w_keys, const float* __restrict__ proxy,
                        const float* __restrict__ gatek, const float* __restrict__ p,
                        const int* __restrict__ adj_row, const int* __restrict__ new_idx,
                        float* __restrict__ ss_rel, float* __restrict__ att_n,
                        float* __restrict__ att_t, short* __restrict__ reb,
                        short* __restrict__ rwb, short* __restrict__ pn,
                        short* __restrict__ proxyb, short* __restrict__ BG,
                        short* __restrict__ Bt2, float* __restrict__ tp,
                        int* __restrict__ rs, unsigned char* __restrict__ flag,
                        float* __restrict__ pout, int R_, int n, int e, int ksel){
  __shared__ float tile[32][33];
  __shared__ float sm[4];
  const int b = blockIdx.x, tid = threadIdx.x;
  const int lane = tid & 63, wv = tid >> 6;

  if(b < R_){
    // ---- relprep ----
    int r = b, d = tid;
    float v = rel_emb[(size_t)r*D+d];
    reb[(size_t)r*D+d] = cvt_bf16(v);
    float s = waveSum(v*v);
    if(lane==0) sm[wv]=s;
    __syncthreads();
    if(tid==0) ss_rel[r]=sm[0]+sm[1]+sm[2]+sm[3];
    __syncthreads();
    for(int l=0;l<2;l++){
      float dd = waveSum(v*attn[l*D+d]);
      if(lane==0) sm[wv]=dd;
      __syncthreads();
      if(tid==0) att_n[(size_t)l*R_+r]=sm[0]+sm[1]+sm[2]+sm[3];
      __syncthreads();
    }
  } else if(b < 3*R_){
    // ---- relW ----
    int l = (b-R_) / R_, r = (b-R_) % R_, d = tid;
    const float* W = w_keys + (size_t)l*D*D;
    const float* ak = attn + (size_t)l*D;
    const float* row = rel_emb + (size_t)r*D;
    float acc=0.f;
#pragma unroll 4
    for(int k=0;k<D;k++) acc = fmaf(row[k], W[(size_t)k*D+d], acc);
    rwb[(size_t)l*R_*D + (size_t)r*D + d]=cvt_bf16(acc);
    float dd = waveSum(acc*ak[d]);
    if(lane==0) sm[wv]=dd;
    __syncthreads();
    if(tid==0) att_t[(size_t)l*R_+r]=sm[0]+sm[1]+sm[2]+sm[3];
  } else if(b < 3*R_+128){
    // ---- proxy: l2-normalized pn + plain bf16 cast proxyb ----
    int j = b - 3*R_;
    float v0 = proxy[(size_t)j*DCAT + tid];
    float v1 = proxy[(size_t)j*DCAT + 256 + tid];
    float v2 = proxy[(size_t)j*DCAT + 512 + tid];
    proxyb[(size_t)j*DCAT + tid]       = cvt_bf16(v0);
    proxyb[(size_t)j*DCAT + 256 + tid] = cvt_bf16(v1);
    proxyb[(size_t)j*DCAT + 512 + tid] = cvt_bf16(v2);
    float ssum = waveSum(v0*v0 + v1*v1 + v2*v2);
    if(lane==0) sm[wv]=ssum;
    __syncthreads();
    float scale = rsqrtf(fmaxf(sm[0]+sm[1]+sm[2]+sm[3],1e-12f));
    pn[(size_t)j*DCAT + tid]       = cvt_bf16(v0*scale);
    pn[(size_t)j*DCAT + 256 + tid] = cvt_bf16(v1*scale);
    pn[(size_t)j*DCAT + 512 + tid] = cvt_bf16(v2*scale);
  } else if(b < 3*R_+128+576+96){
    // ---- transpose-cast tiles ----
    const float* in; short* out; int R, C, ldo, t;
    if(b < 3*R_+128+576){ t = b-(3*R_+128);     in=gatek; out=BG;  R=DCAT; C=DCAT; ldo=QSTR; }
    else                { t = b-(3*R_+128+576); in=proxy; out=Bt2; R=NPX;  C=DCAT; ldo=NPX;  }
    int bx = (t%24)*32, by = (t/24)*32;
    int tx = tid & 31, ty = tid >> 5;
    for(int i=ty;i<32;i+=8){
      int rr = by+i, cc = bx+tx;
      if(rr<R && cc<C) tile[i][tx] = in[(size_t)rr*C + cc];
    }
    __syncthreads();
    for(int i=ty;i<32;i+=8){
      int cc = bx+i, rr = by+tx;
      if(cc<C && rr<R) out[(size_t)cc*ldo + rr] = cvt_bf16(tile[tx][i]);
    }
  } else {
    // ---- prep: tanh(p), rowstart binsearch, flag, p copy ----
    int t = b - (3*R_+128+576+96);
    int i = t*256 + tid;
    if(i<n){ float pv = p[i]; tp[i]=tanhf(pv); pout[i]=pv; }
    if(i<=n){
      int lo=0, hi=e;
      while(lo<hi){ int mid=(lo+hi)>>1; if(adj_row[mid]<i) lo=mid+1; else hi=mid; }
      rs[i]=lo;
    }
    if(i<ksel) flag[new_idx[i]] = 1;
  }
}

// transpose-cast (standalone, for MxTn after k_gemm)
__global__ void k_tcast(const float* __restrict__ in, short* __restrict__ out,
                        int R, int C, int ldo, int coff, float sign){
  __shared__ float tile[32][33];
  int bx = blockIdx.x*32, by = blockIdx.y*32;
  for(int i=threadIdx.y;i<32;i+=8){
    int rr = by+i, cc = bx+threadIdx.x;
    if(rr<R && cc<C) tile[i][threadIdx.x] = in[(size_t)rr*C + cc];
  }
  __syncthreads();
  for(int i=threadIdx.y;i<32;i+=8){
    int cc = bx+i, rr = by+threadIdx.x;
    if(cc<C && rr<R) out[(size_t)cc*ldo + coff + rr] = cvt_bf16(sign*tile[threadIdx.x][i]);
  }
}

// one block per row: write Q cols 0..255 and init ssn[row] = sum of squares
__global__ void k_init0(const float* __restrict__ features, const float* __restrict__ tp,
                        short* __restrict__ Q, float* __restrict__ ssn, int n){
  __shared__ float sm[4];
  int row = blockIdx.x, d = threadIdx.x;
  float v = features[(size_t)row*D + d] * tp[row];
  Q[(size_t)row*QSTR + d] = cvt_bf16(v);
  int lane=d&63, wid=d>>6;
  float s = waveSum(v*v);
  if(lane==0) sm[wid]=s;
  __syncthreads();
  if(d==0) ssn[row] = sm[0]+sm[1]+sm[2]+sm[3];
}

// one wave per node; single fused logit pass + metadata AND vector prefetch
// (R13-exact arithmetic; only load issue timing moved — bit-exact)
__global__ void k_agg(const int* __restrict__ rs, const int* __restrict__ adj_col,
                      const int* __restrict__ rel_ids, const float* __restrict__ rel_vals,
                      const unsigned char* __restrict__ flag, const float* __restrict__ tp,
                      const float* __restrict__ ss_rel, const float* __restrict__ att_n,
                      const float* __restrict__ att_t, const short* __restrict__ reb,
                      const short* __restrict__ rwb, short* __restrict__ Q,
                      float* __restrict__ ssn, int n, int layer){
  int wid = threadIdx.x>>6, lane = threadIdx.x&63;
  int node = blockIdx.x*4 + wid;
  if(node>=n) return;
  int s = rs[node], e = rs[node+1];
  float accq[16];
#pragma unroll
  for(int k=0;k<16;k++) accq[k]=0.f;

  auto logit = [&](int i)->float{
    int rid = rel_ids[i]; float rv = rel_vals[i];
    float a = 0.f;
    if(rv>0.f){
      float t = tp[adj_col[i]];
      float sc = rv*rsqrtf(fmaxf(rv*rv*ss_rel[rid],1e-12f));
      a = t*sc*(flag[i]? att_t[rid] : att_n[rid]);
    }
    return a;
  };

  if(e > s){
    // single logit pass: per-lane aF (edge s+lane) + strided max
    float aF = 0.f, mxl = -INFINITY;
    {
      int i = s + lane;
      if(i < e){
        aF = logit(i);
        mxl = aF;
        for(i += 64; i < e; i += 64) mxl = fmaxf(mxl, logit(i));
      }
    }
    float mx = waveMax(mxl);
    float sel = (s+lane < e) ? __expf(aF - mx) : 0.f;
    for(int i = s+64+lane; i < e; i += 64) sel += __expf(logit(i) - mx);
    float se = waveSum(sel);
    float inv = 1.f/se;

    int qid = lane>>4, ql = lane&15;
    // prefetch group 0: metadata AND vectors
    int j0 = s + qid;
    bool valid = j0 < e;
    int col=0, rid=0; float rv=0.f; bool fl=false;
    bf16x8 pn0={}, pn1={}, pr0={}, pr1={};
    if(valid){
      col=adj_col[j0]; rid=rel_ids[j0]; rv=rel_vals[j0]; fl=flag[j0];
      const short* np = Q + (size_t)col*QSTR + layer*D + ql*16;
      pn0 = *(const bf16x8*)np; pn1 = *(const bf16x8*)(np+8);
      if(rv>0.f){
        const short* rp = (fl? rwb : reb) + (size_t)rid*D + ql*16;
        pr0 = *(const bf16x8*)rp; pr1 = *(const bf16x8*)(rp+8);
      }
    }
    for(int i0=s; i0<e; i0+=4){
      // prefetch next group (loads only — arithmetic untouched)
      int jn = i0 + 4 + qid;
      bool vn = jn < e;
      int coln=0, ridn=0; float rvn=0.f; bool fln=false;
      bf16x8 qn0={}, qn1={}, qr0={}, qr1={};
      if(vn){
        coln=adj_col[jn]; ridn=rel_ids[jn]; rvn=rel_vals[jn]; fln=flag[jn];
        const short* np = Q + (size_t)coln*QSTR + layer*D + ql*16;
        qn0 = *(const bf16x8*)np; qn1 = *(const bf16x8*)(np+8);
        if(rvn>0.f){
          const short* rp = (fln? rwb : reb) + (size_t)ridn*D + ql*16;
          qr0 = *(const bf16x8*)rp; qr1 = *(const bf16x8*)(rp+8);
        }
      }
      // compute current group (identical expressions to R13)
      float w=0.f, coef=0.f;
      float nbv[16], rbv[16];
#pragma unroll
      for(int k=0;k<8;k++){
        nbv[k]=bf2f(pn0[k]); nbv[k+8]=bf2f(pn1[k]);
        rbv[k]=bf2f(pr0[k]); rbv[k+8]=bf2f(pr1[k]);
      }
      if(valid){
        if(rv>0.f){
          float t = tp[col];
          float sc = rv*rsqrtf(fmaxf(rv*rv*ss_rel[rid],1e-12f));
          float dp = 0.f;
#pragma unroll
          for(int k=0;k<16;k++) dp += nbv[k]*rbv[k];
#pragma unroll
          for(int o=1;o<16;o<<=1) dp += __shfl_xor(dp,o,64);
          float a = t*sc*(fl? att_t[rid] : att_n[rid]);
          w = __expf(a-mx)*inv;
          coef = 2.f*t*t*sc*sc*dp;
        } else {
          w = __expf(-mx)*inv;
        }
      }
#pragma unroll
      for(int k=0;k<16;k++) accq[k] += w*(nbv[k] - coef*rbv[k]);

      valid=vn; col=coln; rid=ridn; rv=rvn; fl=fln;
      pn0=qn0; pn1=qn1; pr0=qr0; pr1=qr1;
    }
  }
#pragma unroll
  for(int k=0;k<16;k++){
    float v = accq[k];
    v += __shfl_xor(v,16,64);
    v += __shfl_xor(v,32,64);
    accq[k] = v;
  }
  if(lane < 16){
    float t0 = tp[node];
    bf16x8 o0, o1;
    float pss = 0.f;
#pragma unroll
    for(int k=0;k<8;k++){
      o0[k]=cvt_bf16(accq[k]*t0); o1[k]=cvt_bf16(accq[k+8]*t0);
      pss += accq[k]*accq[k] + accq[k+8]*accq[k+8];
    }
    short* op = Q + (size_t)node*QSTR + (layer+1)*D + lane*16;
    *(bf16x8*)op = o0;
    *(bf16x8*)(op+8) = o1;
#pragma unroll
    for(int o=1;o<16;o<<=1) pss += __shfl_xor(pss,o,64);
    if(lane==0) ssn[node] += pss * t0 * t0;
  }
}

// ---------------- generic MFMA GEMM (ring-3, fp32 out) — used for Mx only ----------
template<int LDA_, int LDB_, int NTOT, int KC>
__global__ __launch_bounds__(256,2) void k_gemm(
    const short* __restrict__ A, const short* __restrict__ Bt,
    float* __restrict__ outF, int M)
{
  __shared__ short smem[3][2][128*32];
  const int tid = threadIdx.x;
  const int lane = tid & 63, w = tid >> 6;
  const int wm = w >> 1, wn = w & 1;
  const int bn = blockIdx.x * 128, bm = blockIdx.y * 128;

  const short* Ag = A  + (size_t)bm * LDA_;
  const short* Bg = Bt + (size_t)bn * LDB_;

  auto stage = [&](int buf, int k0){
#pragma unroll
    for(int c=0;c<2;++c){
      int u = c*256 + tid;
      int row = u >> 2;
      int cb = ((u & 3) ^ ((u >> 3) & 3)) * 8;
      __builtin_amdgcn_global_load_lds(
        (const __attribute__((address_space(1))) unsigned int*)(Ag + (size_t)row*LDA_ + k0 + cb),
        (__attribute__((address_space(3))) unsigned int*)&smem[buf][0][u*8], 16, 0, 0);
      __builtin_amdgcn_global_load_lds(
        (const __attribute__((address_space(1))) unsigned int*)(Bg + (size_t)row*LDB_ + k0 + cb),
        (__attribute__((address_space(3))) unsigned int*)&smem[buf][1][u*8], 16, 0, 0);
    }
  };

  f32x4 acc[4][4] = {};
  const int lr = lane & 15, kg = lane >> 4;
  const int ksw = (kg ^ ((lr >> 1) & 3)) * 8;
  constexpr int NT = KC / 32;

  stage(0, 0);
  stage(1, 32);
  for(int t=0; t<NT; ++t){
    if(t+1 < NT) asm volatile("s_waitcnt vmcnt(4)" ::: "memory");
    else         asm volatile("s_waitcnt vmcnt(0)" ::: "memory");
    __builtin_amdgcn_s_barrier();
    __builtin_amdgcn_sched_barrier(0);
    const short* Al = &smem[t%3][0][0];
    const short* Bl = &smem[t%3][1][0];
    bf16x8 af[4], bfr[4];
#pragma unroll
    for(int i=0;i<4;++i) af[i] = *(const bf16x8*)(Al + (wm*64 + i*16 + lr)*32 + ksw);
#pragma unroll
    for(int j=0;j<4;++j) bfr[j] = *(const bf16x8*)(Bl + (wn*64 + j*16 + lr)*32 + ksw);
    if(t+2 < NT) stage((t+2)%3, (t+2)*32);
    __builtin_amdgcn_s_setprio(1);
#pragma unroll
    for(int i=0;i<4;++i)
#pragma unroll
      for(int j=0;j<4;++j)
        acc[i][j] = __builtin_amdgcn_mfma_f32_16x16x32_bf16(af[i], bfr[j], acc[i][j], 0, 0, 0);
    __builtin_amdgcn_s_setprio(0);
  }

  const int row0 = bm + wm*64 + (lane>>4)*4;
  const int col0 = bn + wn*64 + lr;
#pragma unroll
  for(int i=0;i<4;++i)
#pragma unroll
    for(int j=0;j<4;++j)
#pragma unroll
      for(int r=0;r<4;++r){
        int row = row0 + i*16 + r;
        if(row < M) outF[(size_t)row*NTOT + col0 + j*16] = acc[i][j][r];
      }
}

// ---------------- k_pr: proxy-att logits GEMM (K=768) + fused row softmax ---------
__global__ __launch_bounds__(256,2) void k_pr(
    short* __restrict__ Q, const short* __restrict__ pn,
    const float* __restrict__ ssn, int M)
{
  __shared__ short smem[3][2][128*32];
  const int tid = threadIdx.x, lane = tid & 63, w = tid >> 6;
  const int wm = w >> 1, wn = w & 1;
  int nwg = gridDim.y;
  int orig = blockIdx.y;
  int q = nwg>>3, rm = nwg&7, xcd = orig&7, lid = orig>>3;
  int wg = (xcd<rm ? xcd*(q+1) : rm*(q+1)+(xcd-rm)*q) + lid;
  const int bm = wg*128;

  const short* Ag = Q + (size_t)bm * QSTR;
  const short* Bg = pn;

  auto stage = [&](int buf, int k0){
#pragma unroll
    for(int c=0;c<2;++c){
      int u = c*256 + tid;
      int row = u >> 2;
      int cb = ((u & 3) ^ ((u >> 3) & 3)) * 8;
      __builtin_amdgcn_global_load_lds(
        (const __attribute__((address_space(1))) unsigned int*)(Ag + (size_t)row*QSTR + k0 + cb),
        (__attribute__((address_space(3))) unsigned int*)&smem[buf][0][u*8], 16, 0, 0);
      __builtin_amdgcn_global_load_lds(
        (const __attribute__((address_space(1))) unsigned int*)(Bg + (size_t)row*DCAT + k0 + cb),
        (__attribute__((address_space(3))) unsigned int*)&smem[buf][1][u*8], 16, 0, 0);
    }
  };

  f32x4 acc[4][4] = {};
  const int lr = lane & 15, kg = lane >> 4;
  const int ksw = (kg ^ ((lr >> 1) & 3)) * 8;
  constexpr int NT = DCAT / 32;

  stage(0, 0);
  stage(1, 32);
  for(int t=0; t<NT; ++t){
    if(t+1 < NT) asm volatile("s_waitcnt vmcnt(4)" ::: "memory");
    else         asm volatile("s_waitcnt vmcnt(0)" ::: "memory");
    __builtin_amdgcn_s_barrier();
    __builtin_amdgcn_sched_barrier(0);
    const short* Al = &smem[t%3][0][0];
    const short* Bl = &smem[t%3][1][0];
    bf16x8 af[4], bfr[4];
#pragma unroll
    for(int i=0;i<4;++i) af[i] = *(const bf16x8*)(Al + (wm*64 + i*16 + lr)*32 + ksw);
#pragma unroll
    for(int j=0;j<4;++j) bfr[j] = *(const bf16x8*)(Bl + (wn*64 + j*16 + lr)*32 + ksw);
    if(t+2 < NT) stage((t+2)%3, (t+2)*32);
    __builtin_amdgcn_s_setprio(1);
#pragma unroll
    for(int i=0;i<4;++i)
#pragma unroll
      for(int j=0;j<4;++j)
        acc[i][j] = __builtin_amdgcn_mfma_f32_16x16x32_bf16(af[i], bfr[j], acc[i][j], 0, 0, 0);
    __builtin_amdgcn_s_setprio(0);
  }

  // logits -> LDS bf16 [128][132]
  __syncthreads();
  short* lg = (short*)smem;
  const int row0l = wm*64 + kg*4;
  const int col0l = wn*64 + lr;
#pragma unroll
  for(int i=0;i<4;++i){
#pragma unroll
    for(int j=0;j<4;++j){
#pragma unroll
      for(int r=0;r<4;++r){
        int rl = row0l + i*16 + r;
        int rg = bm + rl;
        float s = (rg < M) ? rsqrtf(fmaxf(ssn[rg],1e-12f)) : 0.f;
        lg[rl*132 + col0l + j*16] = cvt_bf16(acc[i][j][r] * s);
      }
    }
  }
  __syncthreads();
  for(int k2=0;k2<32;++k2){
    int rl = w*32 + k2;
    float a = bf2f(lg[rl*132 + lane]);
    float b = bf2f(lg[rl*132 + 64 + lane]);
    float m = waveMax(fmaxf(a,b));
    float ea = __expf(a-m), eb = __expf(b-m);
    float sm_ = waveSum(ea+eb);
    float inv = 1.f/sm_;
    size_t rg = (size_t)(bm + rl);
    Q[rg*QSTR + DCAT + lane]      = cvt_bf16(ea*inv);
    Q[rg*QSTR + DCAT + 64 + lane] = cvt_bf16(eb*inv);
  }
}

// ---------------- k_go: fused gate GEMM + output (128² ring-3, accepted ceiling) ---
__global__ __launch_bounds__(256,2) void k_go(
    short* __restrict__ Q, const short* __restrict__ BG,
    const short* __restrict__ Bt2, float* __restrict__ outF, int M)
{
  __shared__ short smem[3][2][128*32];
  const int tid = threadIdx.x, lane = tid & 63, w = tid >> 6;
  const int wm = w >> 1, wn = w & 1;
  const int gx = gridDim.x;
  int nwg = gx*gridDim.y;
  int orig = blockIdx.y*gx + blockIdx.x;
  int q = nwg>>3, rm = nwg&7, xcd = orig&7, lid = orig>>3;
  int wg = (xcd<rm ? xcd*(q+1) : rm*(q+1)+(xcd-rm)*q) + lid;
  const int bn = (wg%gx)*128, bm = (wg/gx)*128;
  const int lr = lane & 15, kg = lane >> 4;

  const short* Ag = Q  + (size_t)bm * QSTR;
  const short* Bg = BG + (size_t)bn * QSTR;

  auto stage = [&](int buf, int k0){
#pragma unroll
    for(int c=0;c<2;++c){
      int u = c*256 + tid;
      int row = u >> 2;
      int cb = ((u & 3) ^ ((u >> 3) & 3)) * 8;
      __builtin_amdgcn_global_load_lds(
        (const __attribute__((address_space(1))) unsigned int*)(Ag + (size_t)row*QSTR + k0 + cb),
        (__attribute__((address_space(3))) unsigned int*)&smem[buf][0][u*8], 16, 0, 0);
      __builtin_amdgcn_global_load_lds(
        (const __attribute__((address_space(1))) unsigned int*)(Bg + (size_t)row*QSTR + k0 + cb),
        (__attribute__((address_space(3))) unsigned int*)&smem[buf][1][u*8], 16, 0, 0);
    }
  };

  stage(0, 0);
  stage(1, 32);

  // ---- phase A: pv = P @ Bt2^T (K=128, direct global MFMA) ----
  f32x4 acc[4][4] = {};
#pragma unroll
  for(int ks=0; ks<4; ++ks){
    bf16x8 af[4], bb[4];
#pragma unroll
    for(int i=0;i<4;++i)
      af[i] = *(const bf16x8*)(Q + (size_t)(bm + wm*64 + i*16 + lr)*QSTR + DCAT + ks*32 + kg*8);
#pragma unroll
    for(int j=0;j<4;++j)
      bb[j] = *(const bf16x8*)(Bt2 + (size_t)(bn + wn*64 + j*16 + lr)*NPX + ks*32 + kg*8);
#pragma unroll
    for(int i=0;i<4;++i)
#pragma unroll
      for(int j=0;j<4;++j)
        acc[i][j] = __builtin_amdgcn_mfma_f32_16x16x32_bf16(af[i], bb[j], acc[i][j], 0, 0, 0);
  }
  short4 pvb[4][4];
#pragma unroll
  for(int i=0;i<4;++i)
#pragma unroll
    for(int j=0;j<4;++j){
      pvb[i][j].x = cvt_bf16(acc[i][j][0]);
      pvb[i][j].y = cvt_bf16(acc[i][j][1]);
      pvb[i][j].z = cvt_bf16(acc[i][j][2]);
      pvb[i][j].w = cvt_bf16(acc[i][j][3]);
      acc[i][j] = (f32x4){0.f,0.f,0.f,0.f};
    }

  // ---- main loop: gate logits, K=896, ring-3 counted vmcnt ----
  const int ksw = (kg ^ ((lr >> 1) & 3)) * 8;
  constexpr int NT = QSTR / 32;   // 28
  for(int t=0; t<NT; ++t){
    if(t+1 < NT) asm volatile("s_waitcnt vmcnt(4)" ::: "memory");
    else         asm volatile("s_waitcnt vmcnt(0)" ::: "memory");
    __builtin_amdgcn_s_barrier();
    __builtin_amdgcn_sched_barrier(0);
    const short* Al = &smem[t%3][0][0];
    const short* Bl = &smem[t%3][1][0];
    bf16x8 af[4], bfr[4];
#pragma unroll
    for(int i=0;i<4;++i) af[i] = *(const bf16x8*)(Al + (wm*64 + i*16 + lr)*32 + ksw);
#pragma unroll
    for(int j=0;j<4;++j) bfr[j] = *(const bf16x8*)(Bl + (wn*64 + j*16 + lr)*32 + ksw);
    if(t+2 < NT) stage((t+2)%3, (t+2)*32);
    __builtin_amdgcn_s_setprio(1);
#pragma unroll
    for(int i=0;i<4;++i)
#pragma unroll
      for(int j=0;j<4;++j)
        acc[i][j] = __builtin_amdgcn_mfma_f32_16x16x32_bf16(af[i], bfr[j], acc[i][j], 0, 0, 0);
    __builtin_amdgcn_s_setprio(0);
  }

  // ---- epilogue: out = oc - (1-g)*pv ----
  __syncthreads();
  short* cst = (short*)smem;
  const int row0l = wm*64 + kg*4;
  const int col0l = wn*64 + lr;
#pragma unroll
  for(int i=0;i<4;++i){
#pragma unroll
    for(int j=0;j<4;++j){
      float pv4[4] = { bf2f(pvb[i][j].x), bf2f(pvb[i][j].y), bf2f(pvb[i][j].z), bf2f(pvb[i][j].w) };
#pragma unroll
      for(int r2=0;r2<4;++r2){
        float g = 1.f/(1.f+__expf(-acc[i][j][r2]));
        cst[(row0l + i*16 + r2)*CSTR + col0l + j*16] = cvt_bf16((1.f-g)*pv4[r2]);
      }
    }
  }
  __syncthreads();
  const int rl0 = tid>>4, c0 = (tid&15)*8;
#pragma unroll
  for(int rr=0; rr<8; ++rr){
    int rl = rl0 + rr*16;
    int rg = bm + rl;
    if(rg >= M) continue;
    bf16x8 c8  = *(const bf16x8*)(cst + rl*CSTR + c0);
    bf16x8 oc8 = *(const bf16x8*)(Q + (size_t)rg*QSTR + bn + c0);
    float ov[8];
#pragma unroll
    for(int k=0;k<8;k++) ov[k] = bf2f(oc8[k]) - bf2f(c8[k]);
    *(float4*)(outF + (size_t)rg*DCAT + bn + c0)     = make_float4(ov[0],ov[1],ov[2],ov[3]);
    *(float4*)(outF + (size_t)rg*DCAT + bn + c0 + 4) = make_float4(ov[4],ov[5],ov[6],ov[7]);
  }
}

extern "C" void kernel_launch(void* const* d_in, const int* in_sizes, int n_in,
                              void* d_out, int out_size, void* d_ws, size_t ws_size,
                              hipStream_t stream){
  const float* features = (const float*)d_in[0];
  const float* rel_emb  = (const float*)d_in[1];
  const float* p        = (const float*)d_in[2];
  const float* w_keys   = (const float*)d_in[3];
  const float* attn     = (const float*)d_in[4];
  const float* proxy    = (const float*)d_in[5];
  const float* gatek    = (const float*)d_in[6];
  const float* rel_vals = (const float*)d_in[7];
  const int* adj_row    = (const int*)d_in[8];
  const int* adj_col    = (const int*)d_in[9];
  const int* rel_ids    = (const int*)d_in[10];
  const int* new_idx    = (const int*)d_in[11];

  const int n    = in_sizes[2];
  const int r    = in_sizes[1]/D;
  const int e    = in_sizes[7];
  const int ksel = in_sizes[11];
  const size_t Mpad = ((size_t)n + 127) & ~(size_t)127;

  char* ws = (char*)d_ws;
  size_t off=0;
  auto alloc=[&](size_t bytes)->void*{ void* pp = ws+off; off=(off+bytes+255)&~(size_t)255; return pp; };
  float* tp      = (float*)alloc((size_t)n*4);
  int*   rs      = (int*)alloc((size_t)(n+1)*4);
  unsigned char* flag = (unsigned char*)alloc((size_t)e);
  float* ss_rel  = (float*)alloc((size_t)r*4);
  float* att_n   = (float*)alloc((size_t)2*r*4);
  float* att_t   = (float*)alloc((size_t)2*r*4);
  short* reb     = (short*)alloc((size_t)r*D*2);
  short* rwb     = (short*)alloc((size_t)2*r*D*2);
  short* pn      = (short*)alloc((size_t)NPX*DCAT*2);
  short* proxyb  = (short*)alloc((size_t)NPX*DCAT*2);
  short* Bt2     = (short*)alloc((size_t)DCAT*NPX*2);
  short* BG      = (short*)alloc((size_t)DCAT*QSTR*2);
  float* MxF     = (float*)alloc((size_t)NPX*DCAT*4);
  float* ssn     = (float*)alloc(Mpad*4);
  short* Q       = (short*)alloc(Mpad*QSTR*2);

  float* outF = (float*)d_out;
  float* pout = (float*)d_out + (size_t)n*DCAT;

  hipMemsetAsync(flag, 0, (size_t)e, stream);
  hipMemsetAsync(Q + (size_t)n*QSTR, 0, (Mpad-(size_t)n)*QSTR*2, stream);

  // merged setup: relprep + relW + proxy + tcasts + prep
  {
    int prep_n = (ksel > n+1 ? ksel : n+1);
    int nprep = (prep_n+255)/256;
    int nblocks = 3*r + 128 + 576 + 96 + nprep;
    k_setup<<<nblocks,256,0,stream>>>(rel_emb, attn, w_keys, proxy, gatek, p,
                                      adj_row, new_idx,
                                      ss_rel, att_n, att_t, reb, rwb, pn, proxyb,
                                      BG, Bt2, tp, rs, flag, pout, r, n, e, ksel);
  }
  // Mx = proxy @ gk, then -Mx^T into BG cols 768..895
  k_gemm<DCAT, QSTR, DCAT, DCAT><<<dim3(DCAT/128,1),256,0,stream>>>(proxyb, BG, MxF, NPX);
  k_tcast<<<dim3(DCAT/32, NPX/32), dim3(32,8), 0, stream>>>(MxF, BG, NPX, DCAT, QSTR, DCAT, -1.f);

  k_init0<<<n,256,0,stream>>>(features,tp,Q,ssn,n);
  for(int l=0;l<2;l++)
    k_agg<<<(n+3)/4,256,0,stream>>>(rs,adj_col,rel_ids,rel_vals,flag,tp,ss_rel,
                                    att_n+(size_t)l*r, att_t+(size_t)l*r, reb,
                                    rwb+(size_t)l*r*D, Q, ssn, n, l);

  int mt = (int)(Mpad/128);
  // k_pr: proxy-att logits + fused l2n + softmax -> probs into Q[:,768:896]
  k_pr<<<dim3(1, mt),256,0,stream>>>(Q, pn, ssn, n);
  // k_go: fused gate + output
  k_go<<<dim3(DCAT/128, mt),256,0,stream>>>(Q, BG, Bt2, outF, n);
}